// Round 10
// baseline (389.391 us; speedup 1.0000x reference)
//
#include <hip/hip_runtime.h>
#include <math.h>

#define HID 36
#define NH 3
#define HD 12
#define PROW 64     // f16 units per packed row: 128B, one aligned L2 line
#define BSHIFT 13   // src-bucket = src >> 13 (13 buckets; sort kept for locality)
#define NBUCK 13
#define PSHIFT 8    // dst partition = dst >> 8 (256 dsts per partition)
#define PCHUNK 2048 // edges per chunk in partition pass (small -> more blocks)
#define SPCAP 9216  // LDS-staged partition edges (mean 8192, sigma ~90)
#define CSRCAP 4096 // LDS-staged csr entries per agg block (mean 2048, sigma 45)
#define NSTEP 4     // fraction-paced supersteps (4 -> c~8/step, enables x8 MLP)

typedef _Float16 f16;

// ---------------- CSR build: atomic-free two-level partition sort ----------
// All cursor atomics in LDS; all scattered writes land in per-partition
// 32KB windows (round-7 lesson: global-atomic cursors + unwindowed 4B
// scatter = 300us write-amplified disaster).

__global__ void hist2_kernel(const int* __restrict__ dst, int* __restrict__ M,
                             int E, int C, int np) {
    __shared__ int h[512];
    int t = threadIdx.x;
    int c = blockIdx.x;
    for (int i = t; i < 512; i += blockDim.x) h[i] = 0;
    __syncthreads();
    int i0 = c * PCHUNK;
    int i1 = min(i0 + PCHUNK, E);
    for (int i = i0 + t; i < i1; i += blockDim.x)
        atomicAdd(&h[dst[i] >> PSHIFT], 1);
    __syncthreads();
    for (int b = t; b < np; b += blockDim.x)
        M[(size_t)b * C + c] = h[b];
}

// per-partition exclusive scan over C chunks (multi-round, 512 thr, carry)
__global__ void base_scan_kernel(const int* __restrict__ M, int* __restrict__ BaseT,
                                 int* __restrict__ T, int C, int np) {
    __shared__ int tmp[512];
    int b = blockIdx.x;
    int t = threadIdx.x;
    int carry = 0;
    for (int base = 0; base < C; base += 512) {
        int idx = base + t;
        int v = (idx < C) ? M[(size_t)b * C + idx] : 0;
        tmp[t] = v;
        __syncthreads();
        for (int ofs = 1; ofs < 512; ofs <<= 1) {
            int x = 0;
            if (t >= ofs) x = tmp[t - ofs];
            __syncthreads();
            tmp[t] += x;
            __syncthreads();
        }
        if (idx < C) BaseT[(size_t)idx * 512 + b] = carry + tmp[t] - v;
        carry += tmp[511];
        __syncthreads();
    }
    if (t == 0) T[b] = carry;
}

__global__ void scan_small_kernel(const int* __restrict__ T, int* __restrict__ poff, int np) {
    __shared__ int tmp[512];
    int t = threadIdx.x;
    int v = (t < np) ? T[t] : 0;
    tmp[t] = v;
    __syncthreads();
    for (int ofs = 1; ofs < 512; ofs <<= 1) {
        int x = 0;
        if (t >= ofs) x = tmp[t - ofs];
        __syncthreads();
        tmp[t] += x;
        __syncthreads();
    }
    int excl = tmp[t] - v;
    if (t < np) poff[t] = excl;
    if (t == np - 1) poff[np] = excl + v;
}

__global__ void part_scatter_kernel(const int* __restrict__ src, const int* __restrict__ dst,
                                    const int* __restrict__ BaseT, const int* __restrict__ poff,
                                    int* __restrict__ part, int E, int np) {
    __shared__ int h[512];
    __shared__ int base[512];
    int t = threadIdx.x;
    int c = blockIdx.x;
    for (int i = t; i < 512; i += blockDim.x) h[i] = 0;
    for (int b = t; b < np; b += blockDim.x)
        base[b] = poff[b] + BaseT[(size_t)c * 512 + b];
    __syncthreads();
    int i0 = c * PCHUNK;
    int i1 = min(i0 + PCHUNK, E);
    for (int i = i0 + t; i < i1; i += blockDim.x) {
        int d = dst[i];
        int bin = d >> PSHIFT;
        int r = atomicAdd(&h[bin], 1);
        part[base[bin] + r] = (src[i] << PSHIFT) | (d & ((1 << PSHIFT) - 1));
    }
}

// one block per partition: LDS counting sort by (dst_local, src_bucket).
// Partition edges staged in LDS on the count pass -> scatter pass reads LDS.
__global__ void bucket_csr_kernel(const int* __restrict__ part, const int* __restrict__ T,
                                  const int* __restrict__ poff,
                                  int* __restrict__ csr, int* __restrict__ off,
                                  int n, int E) {
    __shared__ int cnt[256 * NBUCK];
    __shared__ int psum[512];
    __shared__ int smpart[SPCAP];
    int p = blockIdx.x;
    int t = threadIdx.x;
    int dbase = p << PSHIFT;
    int nd = min(256, n - dbase);
    int nc = nd * NBUCK;
    for (int i = t; i < nc; i += blockDim.x) cnt[i] = 0;
    __syncthreads();
    int cnt_p = T[p];
    int e0 = poff[p];
    const int* pp = part + e0;
    bool fits = (cnt_p <= SPCAP);
    for (int i = t; i < cnt_p; i += blockDim.x) {
        int e = pp[i];
        if (fits) smpart[i] = e;
        atomicAdd(&cnt[(e & 255) * NBUCK + ((e >> PSHIFT) >> BSHIFT)], 1);
    }
    __syncthreads();
    int sum = 0;
    if (t < nd) {
        for (int k = 0; k < NBUCK; ++k) {
            int c = cnt[t * NBUCK + k];
            cnt[t * NBUCK + k] = sum;
            sum += c;
        }
    }
    psum[t] = (t < nd) ? sum : 0;
    __syncthreads();
    for (int ofs = 1; ofs < 512; ofs <<= 1) {
        int x = 0;
        if (t >= ofs) x = psum[t - ofs];
        __syncthreads();
        psum[t] += x;
        __syncthreads();
    }
    int dexcl = (t > 0) ? psum[t - 1] : 0;
    int start = e0 + dexcl;
    if (t < nd) {
        for (int k = 0; k < NBUCK; ++k) cnt[t * NBUCK + k] += start;
        off[dbase + t] = start;
    }
    __syncthreads();
    for (int i = t; i < cnt_p; i += blockDim.x) {
        int e = fits ? smpart[i] : pp[i];
        int s = e >> PSHIFT;
        int idx = (e & 255) * NBUCK + (s >> BSHIFT);
        int pos = atomicAdd(&cnt[idx], 1);
        csr[pos] = s << 6;   // s * PROW
    }
    if (p == 0 && t == 0) off[n] = E;
}

// ---------------- fused node kernels ----------------

__device__ __forceinline__ void edge_accum(uint4 qa, uint4 qb, float ern,
                                           float& denom, float* acc) {
    union { uint4 q[2]; f16 hx[16]; } v;
    v.q[0] = qa;
    v.q[1] = qb;
    float e = (float)v.hx[12] + ern;
    e = (e >= 0.f) ? e : 0.2f * e;
    float w = __expf(e);
    denom += w;
#pragma unroll
    for (int k = 0; k < HD; ++k) acc[k] += w * (float)v.hx[k];
}

// fraction-paced barrier-free sweep, NSTEP=4 supersteps: every lane chip-wide
// sits at the same FRACTION of its own (bucket-sorted) list, holding the L2
// working set to ~3.2MB/XCD; per-step count ~deg/4~8 enables the x8 batch
// (16 uint4 gathers in flight per lane -> 2x MLP vs round 9's x4).
template <bool FITS>
__device__ __forceinline__ void sweep_paced(const int* __restrict__ smbuf,
                                            const int* __restrict__ csre,
                                            int j0, int deg, const f16* __restrict__ pb,
                                            float ern, float& denom, float* acc) {
    int j = j0;
#pragma unroll 1
    for (int s2 = 1; s2 <= NSTEP; ++s2) {
        int jend = j0 + ((deg * s2) >> 2);   // NSTEP == 4
        int c = jend - j;
        for (; c >= 8; c -= 8, j += 8) {
            int o0 = FITS ? smbuf[j]     : csre[j];
            int o1 = FITS ? smbuf[j + 1] : csre[j + 1];
            int o2 = FITS ? smbuf[j + 2] : csre[j + 2];
            int o3 = FITS ? smbuf[j + 3] : csre[j + 3];
            int o4 = FITS ? smbuf[j + 4] : csre[j + 4];
            int o5 = FITS ? smbuf[j + 5] : csre[j + 5];
            int o6 = FITS ? smbuf[j + 6] : csre[j + 6];
            int o7 = FITS ? smbuf[j + 7] : csre[j + 7];
            const uint4* r0 = (const uint4*)(pb + o0);
            const uint4* r1 = (const uint4*)(pb + o1);
            const uint4* r2 = (const uint4*)(pb + o2);
            const uint4* r3 = (const uint4*)(pb + o3);
            const uint4* r4 = (const uint4*)(pb + o4);
            const uint4* r5 = (const uint4*)(pb + o5);
            const uint4* r6 = (const uint4*)(pb + o6);
            const uint4* r7 = (const uint4*)(pb + o7);
            uint4 a0 = r0[0], b0 = r0[1];
            uint4 a1 = r1[0], b1 = r1[1];
            uint4 a2 = r2[0], b2 = r2[1];
            uint4 a3 = r3[0], b3 = r3[1];
            uint4 a4 = r4[0], b4 = r4[1];
            uint4 a5 = r5[0], b5 = r5[1];
            uint4 a6 = r6[0], b6 = r6[1];
            uint4 a7 = r7[0], b7 = r7[1];
            edge_accum(a0, b0, ern, denom, acc);
            edge_accum(a1, b1, ern, denom, acc);
            edge_accum(a2, b2, ern, denom, acc);
            edge_accum(a3, b3, ern, denom, acc);
            edge_accum(a4, b4, ern, denom, acc);
            edge_accum(a5, b5, ern, denom, acc);
            edge_accum(a6, b6, ern, denom, acc);
            edge_accum(a7, b7, ern, denom, acc);
        }
        for (; c >= 4; c -= 4, j += 4) {
            int o0 = FITS ? smbuf[j]     : csre[j];
            int o1 = FITS ? smbuf[j + 1] : csre[j + 1];
            int o2 = FITS ? smbuf[j + 2] : csre[j + 2];
            int o3 = FITS ? smbuf[j + 3] : csre[j + 3];
            const uint4* r0 = (const uint4*)(pb + o0);
            const uint4* r1 = (const uint4*)(pb + o1);
            const uint4* r2 = (const uint4*)(pb + o2);
            const uint4* r3 = (const uint4*)(pb + o3);
            uint4 a0 = r0[0], b0 = r0[1];
            uint4 a1 = r1[0], b1 = r1[1];
            uint4 a2 = r2[0], b2 = r2[1];
            uint4 a3 = r3[0], b3 = r3[1];
            edge_accum(a0, b0, ern, denom, acc);
            edge_accum(a1, b1, ern, denom, acc);
            edge_accum(a2, b2, ern, denom, acc);
            edge_accum(a3, b3, ern, denom, acc);
        }
        for (; c > 0; --c, ++j) {
            int o = FITS ? smbuf[j] : csre[j];
            const uint4* r = (const uint4*)(pb + o);
            edge_accum(r[0], r[1], ern, denom, acc);
        }
    }
}

// h0 = x@W0+b0 ; feat = h0@FCW ; pack {feat12,el}x3 + er  (two reg-GEMMs)
// __launch_bounds__(256,1): grid is 391 blocks (<=2 blocks/CU), so target
// minimum occupancy and let the allocator keep h0[36]+feat[36] in VGPRs —
// the default 64-VGPR cap spilled both arrays to scratch (r8: 69us, 7% VALU).
__global__ void __launch_bounds__(256, 1)
lin0tr_kernel(const float* __restrict__ x, const float* __restrict__ w0,
              const float* __restrict__ b0, const float* __restrict__ fcw,
              const float* __restrict__ al, const float* __restrict__ ar,
              float* __restrict__ h, f16* __restrict__ packed,
              float* __restrict__ er, int n) {
    __shared__ float W0[HID * HID];
    __shared__ float W1[HID * HID];
    __shared__ float Bs[HID], ALs[HID], ARs[HID];
    int t = threadIdx.x;
    for (int i = t; i < HID * HID; i += 256) { W0[i] = w0[i]; W1[i] = fcw[i]; }
    if (t < HID) { Bs[t] = b0[t]; ALs[t] = al[t]; ARs[t] = ar[t]; }
    __syncthreads();
    int node = blockIdx.x * 256 + t;
    if (node >= n) return;
    const float4* xp = (const float4*)(x + (size_t)node * HID);
    float h0[HID];
#pragma unroll
    for (int j = 0; j < HID; ++j) h0[j] = Bs[j];
#pragma unroll
    for (int kk = 0; kk < HID / 4; ++kk) {
        float4 xv = xp[kk];
        const float* w = &W0[(4 * kk) * HID];
#pragma unroll
        for (int j = 0; j < HID; ++j)
            h0[j] += xv.x * w[j] + xv.y * w[HID + j] + xv.z * w[2 * HID + j] + xv.w * w[3 * HID + j];
    }
    float* hp = h + (size_t)node * HID;
#pragma unroll
    for (int j = 0; j < HID; ++j) hp[j] = h0[j];
    float feat[HID];
#pragma unroll
    for (int j = 0; j < HID; ++j) feat[j] = 0.f;
#pragma unroll
    for (int k = 0; k < HID; ++k) {
        float hv = h0[k];
        const float* w = &W1[k * HID];
#pragma unroll
        for (int j = 0; j < HID; ++j) feat[j] += hv * w[j];
    }
    union { f16 hx[48]; uint4 q[6]; } u;
#pragma unroll
    for (int hh = 0; hh < NH; ++hh) {
        float sl = 0.f, sr = 0.f;
#pragma unroll
        for (int d = 0; d < HD; ++d) {
            sl += feat[hh * HD + d] * ALs[hh * HD + d];
            sr += feat[hh * HD + d] * ARs[hh * HD + d];
        }
#pragma unroll
        for (int d = 0; d < HD; ++d) u.hx[hh * 16 + d] = (f16)feat[hh * HD + d];
        u.hx[hh * 16 + 12] = (f16)sl;
        u.hx[hh * 16 + 13] = (f16)0.f;
        u.hx[hh * 16 + 14] = (f16)0.f;
        u.hx[hh * 16 + 15] = (f16)0.f;
        er[node * NH + hh] = sr;
    }
    uint4* prow = (uint4*)(packed + (size_t)node * PROW);
#pragma unroll
    for (int q = 0; q < 6; ++q) prow[q] = u.q[q];
}

// fused: paced barrier-free aggregate (csr staged in LDS, x8 MLP) ->
// hnext, then transform(l+1) via LDS exchange. 192 thr = 64 nodes x 3 heads.
__global__ void __launch_bounds__(192)
aggtr_kernel(const f16* __restrict__ packed_in, const float* __restrict__ er_in,
             const float* __restrict__ hcur,
             const int* __restrict__ off, const int* __restrict__ csr,
             const float* __restrict__ bias, const float* __restrict__ wnext,
             const float* __restrict__ aln, const float* __restrict__ arn,
             float* __restrict__ hnext, f16* __restrict__ packed_out,
             float* __restrict__ er_out, int n) {
    __shared__ float Wsh[HID * HID];
    __shared__ float ALs[HID], ARs[HID];
    __shared__ int smbuf[CSRCAP];  // csr span during sweep; hsh afterwards
    int t = threadIdx.x;
    for (int i = t; i < HID * HID; i += 192) Wsh[i] = wnext[i];
    if (t < HID) { ALs[t] = aln[t]; ARs[t] = arn[t]; }
    int ln = t / 3, hh = t - ln * 3;
    int nb0 = blockIdx.x * 64;
    int node = nb0 + ln;
    bool active = (node < n);

    int e0 = off[nb0];
    int e1 = off[min(nb0 + 64, n)];
    int span = e1 - e0;
    bool fits = (span <= CSRCAP);
    if (fits)
        for (int i = t; i < span; i += 192) smbuf[i] = csr[e0 + i];

    int j0 = 0, deg = 0;
    float ern = 0.f;
    if (active) {
        j0 = off[node] - e0;      // block-local csr index
        deg = off[node + 1] - e0 - j0;
        ern = er_in[node * NH + hh];
    }
    const f16* pb = packed_in + hh * 16;
    const int* csre = csr + e0;
    __syncthreads();

    float denom = 0.f;
    float acc[HD];
#pragma unroll
    for (int k = 0; k < HD; ++k) acc[k] = 0.f;

    if (fits) sweep_paced<true>(smbuf, csre, j0, deg, pb, ern, denom, acc);
    else      sweep_paced<false>(smbuf, csre, j0, deg, pb, ern, denom, acc);
    __syncthreads();  // all threads done reading smbuf before hsh reuse

    // epilogue: hnext = elu(acc/denom + hcur + bias); stage into hsh (=smbuf)
    float* hsh = (float*)smbuf;
    float v[HD];
#pragma unroll
    for (int k = 0; k < HD; ++k) v[k] = 0.f;
    if (active) {
        float inv = 1.f / fmaxf(denom, 1e-9f);
        int base = node * HID + hh * HD;
        const float4* hc = (const float4*)(hcur + base);
        float4 h0 = hc[0], h1 = hc[1], h2 = hc[2];
        float hres[HD] = {h0.x, h0.y, h0.z, h0.w, h1.x, h1.y, h1.z, h1.w, h2.x, h2.y, h2.z, h2.w};
#pragma unroll
        for (int k = 0; k < HD; ++k) {
            float x = acc[k] * inv + hres[k] + bias[hh * HD + k];
            v[k] = (x > 0.f) ? x : expm1f(x);
        }
        float4* hp = (float4*)(hnext + base);
        hp[0] = make_float4(v[0], v[1], v[2], v[3]);
        hp[1] = make_float4(v[4], v[5], v[6], v[7]);
        hp[2] = make_float4(v[8], v[9], v[10], v[11]);
    }
#pragma unroll
    for (int k = 0; k < HD; ++k) hsh[ln * 37 + hh * HD + k] = v[k];
    __syncthreads();

    // transform tail: feat12 = hsh[ln][:] @ Wsh[:, hh*12..], then el/er+pack
    float feat[HD];
#pragma unroll
    for (int d = 0; d < HD; ++d) feat[d] = 0.f;
    const float* hrow = &hsh[ln * 37];
#pragma unroll 4
    for (int k = 0; k < HID; ++k) {
        float hv = hrow[k];
        const float* w = &Wsh[k * HID + hh * HD];
#pragma unroll
        for (int d = 0; d < HD; ++d) feat[d] += hv * w[d];
    }
    if (!active) return;
    float sl = 0.f, sr = 0.f;
#pragma unroll
    for (int d = 0; d < HD; ++d) {
        sl += feat[d] * ALs[hh * HD + d];
        sr += feat[d] * ARs[hh * HD + d];
    }
    union { f16 hx[16]; uint4 q[2]; } o;
#pragma unroll
    for (int d = 0; d < HD; ++d) o.hx[d] = (f16)feat[d];
    o.hx[12] = (f16)sl;
    o.hx[13] = (f16)0.f; o.hx[14] = (f16)0.f; o.hx[15] = (f16)0.f;
    uint4* prow = (uint4*)(packed_out + (size_t)node * PROW + hh * 16);
    prow[0] = o.q[0];
    prow[1] = o.q[1];
    er_out[node * NH + hh] = sr;
}

// fused: aggregate(last layer) -> h3 (in-reg) -> out = h3@OW + ob
__global__ void __launch_bounds__(192)
aggout_kernel(const f16* __restrict__ packed_in, const float* __restrict__ er_in,
              const float* __restrict__ hcur,
              const int* __restrict__ off, const int* __restrict__ csr,
              const float* __restrict__ bias, const float* __restrict__ ow,
              const float* __restrict__ ob, float* __restrict__ out, int n) {
    __shared__ float Wsh[HID * HID];
    __shared__ float OBs[HID];
    __shared__ int smbuf[CSRCAP];
    int t = threadIdx.x;
    for (int i = t; i < HID * HID; i += 192) Wsh[i] = ow[i];
    if (t < HID) OBs[t] = ob[t];
    int ln = t / 3, hh = t - ln * 3;
    int nb0 = blockIdx.x * 64;
    int node = nb0 + ln;
    bool active = (node < n);

    int e0 = off[nb0];
    int e1 = off[min(nb0 + 64, n)];
    int span = e1 - e0;
    bool fits = (span <= CSRCAP);
    if (fits)
        for (int i = t; i < span; i += 192) smbuf[i] = csr[e0 + i];

    int j0 = 0, deg = 0;
    float ern = 0.f;
    if (active) {
        j0 = off[node] - e0;
        deg = off[node + 1] - e0 - j0;
        ern = er_in[node * NH + hh];
    }
    const f16* pb = packed_in + hh * 16;
    const int* csre = csr + e0;
    __syncthreads();

    float denom = 0.f;
    float acc[HD];
#pragma unroll
    for (int k = 0; k < HD; ++k) acc[k] = 0.f;

    if (fits) sweep_paced<true>(smbuf, csre, j0, deg, pb, ern, denom, acc);
    else      sweep_paced<false>(smbuf, csre, j0, deg, pb, ern, denom, acc);
    __syncthreads();

    float* hsh = (float*)smbuf;
    float v[HD];
#pragma unroll
    for (int k = 0; k < HD; ++k) v[k] = 0.f;
    if (active) {
        float inv = 1.f / fmaxf(denom, 1e-9f);
        int base = node * HID + hh * HD;
        const float4* hc = (const float4*)(hcur + base);
        float4 h0 = hc[0], h1 = hc[1], h2 = hc[2];
        float hres[HD] = {h0.x, h0.y, h0.z, h0.w, h1.x, h1.y, h1.z, h1.w, h2.x, h2.y, h2.z, h2.w};
#pragma unroll
        for (int k = 0; k < HD; ++k) {
            float x = acc[k] * inv + hres[k] + bias[hh * HD + k];
            v[k] = (x > 0.f) ? x : expm1f(x);
        }
    }
#pragma unroll
    for (int k = 0; k < HD; ++k) hsh[ln * 37 + hh * HD + k] = v[k];
    __syncthreads();

    float feat[HD];
#pragma unroll
    for (int d = 0; d < HD; ++d) feat[d] = OBs[hh * HD + d];
    const float* hrow = &hsh[ln * 37];
#pragma unroll 4
    for (int k = 0; k < HID; ++k) {
        float hv = hrow[k];
        const float* w = &Wsh[k * HID + hh * HD];
#pragma unroll
        for (int d = 0; d < HD; ++d) feat[d] += hv * w[d];
    }
    if (!active) return;
    float4* op = (float4*)(out + (size_t)node * HID + hh * HD);
    op[0] = make_float4(feat[0], feat[1], feat[2], feat[3]);
    op[1] = make_float4(feat[4], feat[5], feat[6], feat[7]);
    op[2] = make_float4(feat[8], feat[9], feat[10], feat[11]);
}

// ---------------- launch ----------------

extern "C" void kernel_launch(void* const* d_in, const int* in_sizes, int n_in,
                              void* d_out, int out_size, void* d_ws, size_t ws_size,
                              hipStream_t stream) {
    const float* xnf = (const float*)d_in[0];
    const int* src = (const int*)d_in[1];
    const int* dst = (const int*)d_in[2];
    const float* l0w = (const float*)d_in[3];
    const float* l0b = (const float*)d_in[4];
    const float* fcw = (const float*)d_in[5];
    const float* al  = (const float*)d_in[6];
    const float* ar  = (const float*)d_in[7];
    const float* gb  = (const float*)d_in[8];
    const float* ow  = (const float*)d_in[9];
    const float* ob  = (const float*)d_in[10];
    float* out = (float*)d_out;
    const int N = in_sizes[0] / HID;
    const int E = in_sizes[1];
    const int NP = (N + (1 << PSHIFT) - 1) >> PSHIFT;  // 391 dst partitions
    const int C = (E + PCHUNK - 1) / PCHUNK;           // 1563 chunks

    char* p = (char*)d_ws;
    auto alloc = [&](size_t bytes) {
        char* r = p;
        p += (bytes + 255) & ~(size_t)255;
        return r;
    };
    int* part    = (int*)alloc((size_t)E * 4);
    int* M       = (int*)alloc((size_t)NP * C * 4);
    int* BaseT   = (int*)alloc((size_t)C * 512 * 4);
    int* T       = (int*)alloc((size_t)NP * 4);
    int* poff    = (int*)alloc((size_t)(NP + 1) * 4);
    int* off     = (int*)alloc((size_t)(N + 1) * 4);
    int* csr     = (int*)alloc((size_t)E * 4);
    float* ha    = (float*)alloc((size_t)N * HID * 4);
    float* hb    = (float*)alloc((size_t)N * HID * 4);
    f16* pkA     = (f16*)alloc((size_t)N * PROW * 2);
    f16* pkB     = (f16*)alloc((size_t)N * PROW * 2);
    float* erA   = (float*)alloc((size_t)N * NH * 4);
    float* erB   = (float*)alloc((size_t)N * NH * 4);

    // CSR build (atomic-free partition, then per-partition LDS sort)
    hist2_kernel<<<C, 512, 0, stream>>>(dst, M, E, C, NP);
    base_scan_kernel<<<NP, 512, 0, stream>>>(M, BaseT, T, C, NP);
    scan_small_kernel<<<1, 512, 0, stream>>>(T, poff, NP);
    part_scatter_kernel<<<C, 512, 0, stream>>>(src, dst, BaseT, poff, part, E, NP);
    bucket_csr_kernel<<<NP, 512, 0, stream>>>(part, T, poff, csr, off, N, E);

    int nblk = (N + 255) / 256;
    int fblk = (N + 63) / 64;

    // h0 + transform(layer0)
    lin0tr_kernel<<<nblk, 256, 0, stream>>>(xnf, l0w, l0b, fcw, al, ar, ha, pkA, erA, N);

    // layer0 aggregate + transform(layer1)
    aggtr_kernel<<<fblk, 192, 0, stream>>>(pkA, erA, ha, off, csr, gb,
                                           fcw + (size_t)1 * HID * HID, al + HID, ar + HID,
                                           hb, pkB, erB, N);
    // layer1 aggregate + transform(layer2)
    aggtr_kernel<<<fblk, 192, 0, stream>>>(pkB, erB, hb, off, csr, gb + HID,
                                           fcw + (size_t)2 * HID * HID, al + 2 * HID, ar + 2 * HID,
                                           ha, pkA, erA, N);
    // layer2 aggregate + out GEMM (h3 never materialized)
    aggout_kernel<<<fblk, 192, 0, stream>>>(pkA, erA, ha, off, csr, gb + 2 * HID,
                                            ow, ob, out, N);
}

// Round 11
// 367.899 us; speedup vs baseline: 1.0584x; 1.0584x over previous
//
#include <hip/hip_runtime.h>
#include <math.h>

#define HID 36
#define NH 3
#define HD 12
#define PROW 64     // f16 units per packed row: 128B, one aligned L2 line
#define BSHIFT 13   // src-bucket = src >> 13 (13 buckets; sort kept for locality)
#define NBUCK 13
#define PSHIFT 8    // dst partition = dst >> 8 (256 dsts per partition)
#define PCHUNK 2048 // edges per chunk in partition pass
#define SPCAP 9216  // LDS-staged partition edges (mean 8192, sigma ~90)
#define CSRCAP 4096 // LDS-staged csr entries per agg block (mean 2048, sigma 45)
#define NSTEP 8     // fraction-paced supersteps (r10: NSTEP=4/x8 regressed — L2 overflow)

typedef _Float16 f16;

// ---------------- CSR build: atomic-free two-level partition sort ----------
// All cursor atomics in LDS; all scattered writes land in per-partition
// 32KB windows (round-7 lesson). Launch-count trimmed (round-11): lin0tr
// fused with hist2; scan_small deleted (consumers re-scan T in-block).

// fused: blocks [0,nb_lin) run lin0tr; blocks [nb_lin, nb_lin+C) run hist2.
// h0 = x@W0+b0 ; feat = h0@FCW ; pack {feat12,el}x3 + er  (two reg-GEMMs)
// __launch_bounds__(256,1): lin0tr grid is small, keep h0[36]+feat[36] in
// VGPRs (r8: default 64-VGPR cap spilled both arrays -> 69us at 7% VALU).
__global__ void __launch_bounds__(256, 1)
lin0_hist_kernel(const float* __restrict__ x, const float* __restrict__ w0,
                 const float* __restrict__ b0, const float* __restrict__ fcw,
                 const float* __restrict__ al, const float* __restrict__ ar,
                 float* __restrict__ h, f16* __restrict__ packed,
                 float* __restrict__ er, int n, int nb_lin,
                 const int* __restrict__ dst, int* __restrict__ M, int E, int C,
                 int np) {
    int t = threadIdx.x;
    if ((int)blockIdx.x >= nb_lin) {
        // ---- hist2 role ----
        __shared__ int hcnt[512];
        int c = blockIdx.x - nb_lin;
        for (int i = t; i < 512; i += 256) hcnt[i] = 0;
        __syncthreads();
        int i0 = c * PCHUNK;
        int i1 = min(i0 + PCHUNK, E);
        for (int i = i0 + t; i < i1; i += 256)
            atomicAdd(&hcnt[dst[i] >> PSHIFT], 1);
        __syncthreads();
        for (int b = t; b < np; b += 256)
            M[(size_t)b * C + c] = hcnt[b];
        return;
    }
    // ---- lin0tr role ----
    __shared__ float W0[HID * HID];
    __shared__ float W1[HID * HID];
    __shared__ float Bs[HID], ALs[HID], ARs[HID];
    for (int i = t; i < HID * HID; i += 256) { W0[i] = w0[i]; W1[i] = fcw[i]; }
    if (t < HID) { Bs[t] = b0[t]; ALs[t] = al[t]; ARs[t] = ar[t]; }
    __syncthreads();
    int node = blockIdx.x * 256 + t;
    if (node >= n) return;
    const float4* xp = (const float4*)(x + (size_t)node * HID);
    float h0[HID];
#pragma unroll
    for (int j = 0; j < HID; ++j) h0[j] = Bs[j];
#pragma unroll
    for (int kk = 0; kk < HID / 4; ++kk) {
        float4 xv = xp[kk];
        const float* w = &W0[(4 * kk) * HID];
#pragma unroll
        for (int j = 0; j < HID; ++j)
            h0[j] += xv.x * w[j] + xv.y * w[HID + j] + xv.z * w[2 * HID + j] + xv.w * w[3 * HID + j];
    }
    float* hp = h + (size_t)node * HID;
#pragma unroll
    for (int j = 0; j < HID; ++j) hp[j] = h0[j];
    float feat[HID];
#pragma unroll
    for (int j = 0; j < HID; ++j) feat[j] = 0.f;
#pragma unroll
    for (int k = 0; k < HID; ++k) {
        float hv = h0[k];
        const float* w = &W1[k * HID];
#pragma unroll
        for (int j = 0; j < HID; ++j) feat[j] += hv * w[j];
    }
    union { f16 hx[48]; uint4 q[6]; } u;
#pragma unroll
    for (int hh = 0; hh < NH; ++hh) {
        float sl = 0.f, sr = 0.f;
#pragma unroll
        for (int d = 0; d < HD; ++d) {
            sl += feat[hh * HD + d] * ALs[hh * HD + d];
            sr += feat[hh * HD + d] * ARs[hh * HD + d];
        }
#pragma unroll
        for (int d = 0; d < HD; ++d) u.hx[hh * 16 + d] = (f16)feat[hh * HD + d];
        u.hx[hh * 16 + 12] = (f16)sl;
        u.hx[hh * 16 + 13] = (f16)0.f;
        u.hx[hh * 16 + 14] = (f16)0.f;
        u.hx[hh * 16 + 15] = (f16)0.f;
        er[node * NH + hh] = sr;
    }
    uint4* prow = (uint4*)(packed + (size_t)node * PROW);
#pragma unroll
    for (int q = 0; q < 6; ++q) prow[q] = u.q[q];
}

// per-partition exclusive scan over C chunks (multi-round, 512 thr, carry)
__global__ void base_scan_kernel(const int* __restrict__ M, int* __restrict__ BaseT,
                                 int* __restrict__ T, int C, int np) {
    __shared__ int tmp[512];
    int b = blockIdx.x;
    int t = threadIdx.x;
    int carry = 0;
    for (int base = 0; base < C; base += 512) {
        int idx = base + t;
        int v = (idx < C) ? M[(size_t)b * C + idx] : 0;
        tmp[t] = v;
        __syncthreads();
        for (int ofs = 1; ofs < 512; ofs <<= 1) {
            int x = 0;
            if (t >= ofs) x = tmp[t - ofs];
            __syncthreads();
            tmp[t] += x;
            __syncthreads();
        }
        if (idx < C) BaseT[(size_t)idx * 512 + b] = carry + tmp[t] - v;
        carry += tmp[511];
        __syncthreads();
    }
    if (t == 0) T[b] = carry;
}

// scatters edges into partition windows; re-computes poff = excl-scan(T)
// in-block (391 ints, ~free) so the 1-block scan_small launch is deleted.
__global__ void part_scatter_kernel(const int* __restrict__ src, const int* __restrict__ dst,
                                    const int* __restrict__ BaseT, const int* __restrict__ T,
                                    int* __restrict__ part, int E, int np) {
    __shared__ int h[512];
    __shared__ int tsc[512];
    __shared__ int base[512];
    int t = threadIdx.x;
    int c = blockIdx.x;
    int v = (t < np) ? T[t] : 0;
    tsc[t] = v;
    h[t] = 0;
    __syncthreads();
    for (int ofs = 1; ofs < 512; ofs <<= 1) {
        int x = 0;
        if (t >= ofs) x = tsc[t - ofs];
        __syncthreads();
        tsc[t] += x;
        __syncthreads();
    }
    if (t < np) base[t] = (tsc[t] - v) + BaseT[(size_t)c * 512 + t];
    __syncthreads();
    int i0 = c * PCHUNK;
    int i1 = min(i0 + PCHUNK, E);
    for (int i = i0 + t; i < i1; i += blockDim.x) {
        int d = dst[i];
        int bin = d >> PSHIFT;
        int r = atomicAdd(&h[bin], 1);
        part[base[bin] + r] = (src[i] << PSHIFT) | (d & ((1 << PSHIFT) - 1));
    }
}

// one block per partition: LDS counting sort by (dst_local, src_bucket).
// Partition edges staged in LDS on the count pass -> scatter pass reads LDS.
// poff[p] re-computed in-block from T (scan_small deleted).
__global__ void bucket_csr_kernel(const int* __restrict__ part, const int* __restrict__ T,
                                  int* __restrict__ csr, int* __restrict__ off,
                                  int n, int E, int np) {
    __shared__ int cnt[256 * NBUCK];
    __shared__ int psum[512];
    __shared__ int smpart[SPCAP];
    __shared__ int e0s;
    int p = blockIdx.x;
    int t = threadIdx.x;
    // in-block exclusive scan of T to get e0 = poff[p]
    int v = (t < np) ? T[t] : 0;
    psum[t] = v;
    __syncthreads();
    for (int ofs = 1; ofs < 512; ofs <<= 1) {
        int x = 0;
        if (t >= ofs) x = psum[t - ofs];
        __syncthreads();
        psum[t] += x;
        __syncthreads();
    }
    if (t == p) e0s = psum[t] - v;
    __syncthreads();
    int e0 = e0s;
    int dbase = p << PSHIFT;
    int nd = min(256, n - dbase);
    int nc = nd * NBUCK;
    for (int i = t; i < nc; i += blockDim.x) cnt[i] = 0;
    __syncthreads();
    int cnt_p = T[p];
    const int* pp = part + e0;
    bool fits = (cnt_p <= SPCAP);
    for (int i = t; i < cnt_p; i += blockDim.x) {
        int e = pp[i];
        if (fits) smpart[i] = e;
        atomicAdd(&cnt[(e & 255) * NBUCK + ((e >> PSHIFT) >> BSHIFT)], 1);
    }
    __syncthreads();
    int sum = 0;
    if (t < nd) {
        for (int k = 0; k < NBUCK; ++k) {
            int c = cnt[t * NBUCK + k];
            cnt[t * NBUCK + k] = sum;
            sum += c;
        }
    }
    psum[t] = (t < nd) ? sum : 0;
    __syncthreads();
    for (int ofs = 1; ofs < 512; ofs <<= 1) {
        int x = 0;
        if (t >= ofs) x = psum[t - ofs];
        __syncthreads();
        psum[t] += x;
        __syncthreads();
    }
    int dexcl = (t > 0) ? psum[t - 1] : 0;
    int start = e0 + dexcl;
    if (t < nd) {
        for (int k = 0; k < NBUCK; ++k) cnt[t * NBUCK + k] += start;
        off[dbase + t] = start;
    }
    __syncthreads();
    for (int i = t; i < cnt_p; i += blockDim.x) {
        int e = fits ? smpart[i] : pp[i];
        int s = e >> PSHIFT;
        int idx = (e & 255) * NBUCK + (s >> BSHIFT);
        int pos = atomicAdd(&cnt[idx], 1);
        csr[pos] = s << 6;   // s * PROW
    }
    if (p == 0 && t == 0) off[n] = E;
}

// ---------------- fused node kernels (round-9 best agg config) -------------

__device__ __forceinline__ void edge_accum(uint4 qa, uint4 qb, float ern,
                                           float& denom, float* acc) {
    union { uint4 q[2]; f16 hx[16]; } v;
    v.q[0] = qa;
    v.q[1] = qb;
    float e = (float)v.hx[12] + ern;
    e = (e >= 0.f) ? e : 0.2f * e;
    float w = __expf(e);
    denom += w;
#pragma unroll
    for (int k = 0; k < HD; ++k) acc[k] += w * (float)v.hx[k];
}

// fraction-paced barrier-free sweep: NSTEP=8 supersteps; every lane chip-wide
// sits at the same FRACTION of its own (bucket-sorted) list at the same
// iteration (~1.6MB active set per XCD L2). Rows are one aligned 128B line.
// (r10: NSTEP=4/x8 regressed — 3.2MB set overflowed L2, FETCH +16%, dur +7%.)
template <bool FITS>
__device__ __forceinline__ void sweep_paced(const int* __restrict__ smbuf,
                                            const int* __restrict__ csre,
                                            int j0, int deg, const f16* __restrict__ pb,
                                            float ern, float& denom, float* acc) {
    int j = j0;
#pragma unroll 1
    for (int s2 = 1; s2 <= NSTEP; ++s2) {
        int jend = j0 + ((deg * s2) >> 3);   // NSTEP == 8
        int c = jend - j;
        for (; c >= 4; c -= 4, j += 4) {
            int o0 = FITS ? smbuf[j]     : csre[j];
            int o1 = FITS ? smbuf[j + 1] : csre[j + 1];
            int o2 = FITS ? smbuf[j + 2] : csre[j + 2];
            int o3 = FITS ? smbuf[j + 3] : csre[j + 3];
            const uint4* r0 = (const uint4*)(pb + o0);
            const uint4* r1 = (const uint4*)(pb + o1);
            const uint4* r2 = (const uint4*)(pb + o2);
            const uint4* r3 = (const uint4*)(pb + o3);
            uint4 a0 = r0[0], b0 = r0[1];
            uint4 a1 = r1[0], b1 = r1[1];
            uint4 a2 = r2[0], b2 = r2[1];
            uint4 a3 = r3[0], b3 = r3[1];
            edge_accum(a0, b0, ern, denom, acc);
            edge_accum(a1, b1, ern, denom, acc);
            edge_accum(a2, b2, ern, denom, acc);
            edge_accum(a3, b3, ern, denom, acc);
        }
        for (; c > 0; --c, ++j) {
            int o = FITS ? smbuf[j] : csre[j];
            const uint4* r = (const uint4*)(pb + o);
            edge_accum(r[0], r[1], ern, denom, acc);
        }
    }
}

// fused: paced barrier-free aggregate (csr staged in LDS, x4 unroll) ->
// hnext, then transform(l+1) via LDS exchange. 192 thr = 64 nodes x 3 heads.
__global__ void __launch_bounds__(192)
aggtr_kernel(const f16* __restrict__ packed_in, const float* __restrict__ er_in,
             const float* __restrict__ hcur,
             const int* __restrict__ off, const int* __restrict__ csr,
             const float* __restrict__ bias, const float* __restrict__ wnext,
             const float* __restrict__ aln, const float* __restrict__ arn,
             float* __restrict__ hnext, f16* __restrict__ packed_out,
             float* __restrict__ er_out, int n) {
    __shared__ float Wsh[HID * HID];
    __shared__ float ALs[HID], ARs[HID];
    __shared__ int smbuf[CSRCAP];  // csr span during sweep; hsh afterwards
    int t = threadIdx.x;
    for (int i = t; i < HID * HID; i += 192) Wsh[i] = wnext[i];
    if (t < HID) { ALs[t] = aln[t]; ARs[t] = arn[t]; }
    int ln = t / 3, hh = t - ln * 3;
    int nb0 = blockIdx.x * 64;
    int node = nb0 + ln;
    bool active = (node < n);

    int e0 = off[nb0];
    int e1 = off[min(nb0 + 64, n)];
    int span = e1 - e0;
    bool fits = (span <= CSRCAP);
    if (fits)
        for (int i = t; i < span; i += 192) smbuf[i] = csr[e0 + i];

    int j0 = 0, deg = 0;
    float ern = 0.f;
    if (active) {
        j0 = off[node] - e0;      // block-local csr index
        deg = off[node + 1] - e0 - j0;
        ern = er_in[node * NH + hh];
    }
    const f16* pb = packed_in + hh * 16;
    const int* csre = csr + e0;
    __syncthreads();

    float denom = 0.f;
    float acc[HD];
#pragma unroll
    for (int k = 0; k < HD; ++k) acc[k] = 0.f;

    if (fits) sweep_paced<true>(smbuf, csre, j0, deg, pb, ern, denom, acc);
    else      sweep_paced<false>(smbuf, csre, j0, deg, pb, ern, denom, acc);
    __syncthreads();  // all threads done reading smbuf before hsh reuse

    // epilogue: hnext = elu(acc/denom + hcur + bias); stage into hsh (=smbuf)
    float* hsh = (float*)smbuf;
    float v[HD];
#pragma unroll
    for (int k = 0; k < HD; ++k) v[k] = 0.f;
    if (active) {
        float inv = 1.f / fmaxf(denom, 1e-9f);
        int base = node * HID + hh * HD;
        const float4* hc = (const float4*)(hcur + base);
        float4 h0 = hc[0], h1 = hc[1], h2 = hc[2];
        float hres[HD] = {h0.x, h0.y, h0.z, h0.w, h1.x, h1.y, h1.z, h1.w, h2.x, h2.y, h2.z, h2.w};
#pragma unroll
        for (int k = 0; k < HD; ++k) {
            float x = acc[k] * inv + hres[k] + bias[hh * HD + k];
            v[k] = (x > 0.f) ? x : expm1f(x);
        }
        float4* hp = (float4*)(hnext + base);
        hp[0] = make_float4(v[0], v[1], v[2], v[3]);
        hp[1] = make_float4(v[4], v[5], v[6], v[7]);
        hp[2] = make_float4(v[8], v[9], v[10], v[11]);
    }
#pragma unroll
    for (int k = 0; k < HD; ++k) hsh[ln * 37 + hh * HD + k] = v[k];
    __syncthreads();

    // transform tail: feat12 = hsh[ln][:] @ Wsh[:, hh*12..], then el/er+pack
    float feat[HD];
#pragma unroll
    for (int d = 0; d < HD; ++d) feat[d] = 0.f;
    const float* hrow = &hsh[ln * 37];
#pragma unroll 4
    for (int k = 0; k < HID; ++k) {
        float hv = hrow[k];
        const float* w = &Wsh[k * HID + hh * HD];
#pragma unroll
        for (int d = 0; d < HD; ++d) feat[d] += hv * w[d];
    }
    if (!active) return;
    float sl = 0.f, sr = 0.f;
#pragma unroll
    for (int d = 0; d < HD; ++d) {
        sl += feat[d] * ALs[hh * HD + d];
        sr += feat[d] * ARs[hh * HD + d];
    }
    union { f16 hx[16]; uint4 q[2]; } o;
#pragma unroll
    for (int d = 0; d < HD; ++d) o.hx[d] = (f16)feat[d];
    o.hx[12] = (f16)sl;
    o.hx[13] = (f16)0.f; o.hx[14] = (f16)0.f; o.hx[15] = (f16)0.f;
    uint4* prow = (uint4*)(packed_out + (size_t)node * PROW + hh * 16);
    prow[0] = o.q[0];
    prow[1] = o.q[1];
    er_out[node * NH + hh] = sr;
}

// fused: aggregate(last layer) -> h3 (in-reg) -> out = h3@OW + ob
__global__ void __launch_bounds__(192)
aggout_kernel(const f16* __restrict__ packed_in, const float* __restrict__ er_in,
              const float* __restrict__ hcur,
              const int* __restrict__ off, const int* __restrict__ csr,
              const float* __restrict__ bias, const float* __restrict__ ow,
              const float* __restrict__ ob, float* __restrict__ out, int n) {
    __shared__ float Wsh[HID * HID];
    __shared__ float OBs[HID];
    __shared__ int smbuf[CSRCAP];
    int t = threadIdx.x;
    for (int i = t; i < HID * HID; i += 192) Wsh[i] = ow[i];
    if (t < HID) OBs[t] = ob[t];
    int ln = t / 3, hh = t - ln * 3;
    int nb0 = blockIdx.x * 64;
    int node = nb0 + ln;
    bool active = (node < n);

    int e0 = off[nb0];
    int e1 = off[min(nb0 + 64, n)];
    int span = e1 - e0;
    bool fits = (span <= CSRCAP);
    if (fits)
        for (int i = t; i < span; i += 192) smbuf[i] = csr[e0 + i];

    int j0 = 0, deg = 0;
    float ern = 0.f;
    if (active) {
        j0 = off[node] - e0;
        deg = off[node + 1] - e0 - j0;
        ern = er_in[node * NH + hh];
    }
    const f16* pb = packed_in + hh * 16;
    const int* csre = csr + e0;
    __syncthreads();

    float denom = 0.f;
    float acc[HD];
#pragma unroll
    for (int k = 0; k < HD; ++k) acc[k] = 0.f;

    if (fits) sweep_paced<true>(smbuf, csre, j0, deg, pb, ern, denom, acc);
    else      sweep_paced<false>(smbuf, csre, j0, deg, pb, ern, denom, acc);
    __syncthreads();

    float* hsh = (float*)smbuf;
    float v[HD];
#pragma unroll
    for (int k = 0; k < HD; ++k) v[k] = 0.f;
    if (active) {
        float inv = 1.f / fmaxf(denom, 1e-9f);
        int base = node * HID + hh * HD;
        const float4* hc = (const float4*)(hcur + base);
        float4 h0 = hc[0], h1 = hc[1], h2 = hc[2];
        float hres[HD] = {h0.x, h0.y, h0.z, h0.w, h1.x, h1.y, h1.z, h1.w, h2.x, h2.y, h2.z, h2.w};
#pragma unroll
        for (int k = 0; k < HD; ++k) {
            float x = acc[k] * inv + hres[k] + bias[hh * HD + k];
            v[k] = (x > 0.f) ? x : expm1f(x);
        }
    }
#pragma unroll
    for (int k = 0; k < HD; ++k) hsh[ln * 37 + hh * HD + k] = v[k];
    __syncthreads();

    float feat[HD];
#pragma unroll
    for (int d = 0; d < HD; ++d) feat[d] = OBs[hh * HD + d];
    const float* hrow = &hsh[ln * 37];
#pragma unroll 4
    for (int k = 0; k < HID; ++k) {
        float hv = hrow[k];
        const float* w = &Wsh[k * HID + hh * HD];
#pragma unroll
        for (int d = 0; d < HD; ++d) feat[d] += hv * w[d];
    }
    if (!active) return;
    float4* op = (float4*)(out + (size_t)node * HID + hh * HD);
    op[0] = make_float4(feat[0], feat[1], feat[2], feat[3]);
    op[1] = make_float4(feat[4], feat[5], feat[6], feat[7]);
    op[2] = make_float4(feat[8], feat[9], feat[10], feat[11]);
}

// ---------------- launch ----------------

extern "C" void kernel_launch(void* const* d_in, const int* in_sizes, int n_in,
                              void* d_out, int out_size, void* d_ws, size_t ws_size,
                              hipStream_t stream) {
    const float* xnf = (const float*)d_in[0];
    const int* src = (const int*)d_in[1];
    const int* dst = (const int*)d_in[2];
    const float* l0w = (const float*)d_in[3];
    const float* l0b = (const float*)d_in[4];
    const float* fcw = (const float*)d_in[5];
    const float* al  = (const float*)d_in[6];
    const float* ar  = (const float*)d_in[7];
    const float* gb  = (const float*)d_in[8];
    const float* ow  = (const float*)d_in[9];
    const float* ob  = (const float*)d_in[10];
    float* out = (float*)d_out;
    const int N = in_sizes[0] / HID;
    const int E = in_sizes[1];
    const int NP = (N + (1 << PSHIFT) - 1) >> PSHIFT;  // 391 dst partitions
    const int C = (E + PCHUNK - 1) / PCHUNK;           // 1563 chunks

    char* p = (char*)d_ws;
    auto alloc = [&](size_t bytes) {
        char* r = p;
        p += (bytes + 255) & ~(size_t)255;
        return r;
    };
    int* part    = (int*)alloc((size_t)E * 4);
    int* M       = (int*)alloc((size_t)NP * C * 4);
    int* BaseT   = (int*)alloc((size_t)C * 512 * 4);
    int* T       = (int*)alloc((size_t)NP * 4);
    int* off     = (int*)alloc((size_t)(N + 1) * 4);
    int* csr     = (int*)alloc((size_t)E * 4);
    float* ha    = (float*)alloc((size_t)N * HID * 4);
    float* hb    = (float*)alloc((size_t)N * HID * 4);
    f16* pkA     = (f16*)alloc((size_t)N * PROW * 2);
    f16* pkB     = (f16*)alloc((size_t)N * PROW * 2);
    float* erA   = (float*)alloc((size_t)N * NH * 4);
    float* erB   = (float*)alloc((size_t)N * NH * 4);

    int nblk = (N + 255) / 256;
    int fblk = (N + 63) / 64;

    // fused lin0tr + hist2 (independent workloads, one launch)
    lin0_hist_kernel<<<nblk + C, 256, 0, stream>>>(xnf, l0w, l0b, fcw, al, ar,
                                                   ha, pkA, erA, N, nblk,
                                                   dst, M, E, C, NP);
    base_scan_kernel<<<NP, 512, 0, stream>>>(M, BaseT, T, C, NP);
    part_scatter_kernel<<<C, 512, 0, stream>>>(src, dst, BaseT, T, part, E, NP);
    bucket_csr_kernel<<<NP, 512, 0, stream>>>(part, T, csr, off, N, E, NP);

    // layer0 aggregate + transform(layer1)
    aggtr_kernel<<<fblk, 192, 0, stream>>>(pkA, erA, ha, off, csr, gb,
                                           fcw + (size_t)1 * HID * HID, al + HID, ar + HID,
                                           hb, pkB, erB, N);
    // layer1 aggregate + transform(layer2)
    aggtr_kernel<<<fblk, 192, 0, stream>>>(pkB, erB, hb, off, csr, gb + HID,
                                           fcw + (size_t)2 * HID * HID, al + 2 * HID, ar + 2 * HID,
                                           ha, pkA, erA, N);
    // layer2 aggregate + out GEMM (h3 never materialized)
    aggout_kernel<<<fblk, 192, 0, stream>>>(pkA, erA, ha, off, csr, gb + 2 * HID,
                                            ow, ob, out, N);
}

// Round 12
// 337.371 us; speedup vs baseline: 1.1542x; 1.0905x over previous
//
#include <hip/hip_runtime.h>
#include <math.h>

#define HID 36
#define NH 3
#define HD 12
#define PROW 64     // f16 units per packed row: 128B, one aligned L2 line
#define BSHIFT 13   // src-bucket = src >> 13 (13 buckets; sort kept for locality)
#define NBUCK 13
#define PSHIFT 8    // dst partition = dst >> 8 (256 dsts per partition)
#define PCHUNK 2048 // edges per chunk in partition pass
#define SPCAP 9216  // LDS reorder buffer per partition (mean 8192, sigma ~90)
#define CSRCAP 4096 // LDS-staged csr entries per agg block (mean 2048, sigma 45)
#define NSTEP 8     // fraction-paced supersteps (r10: NSTEP=4/x8 regressed — L2 overflow)

typedef _Float16 f16;

// ---------------- CSR build: atomic-free two-level partition sort ----------
// r12: both scatter passes reorder in LDS first, then write global
// COALESCED (r7/r11 lesson: scattered sub-line global writes are the
// build's dominant cost — one TA line-transaction per 4B write).

// fused: blocks [0,nb_lin) run lin0tr; blocks [nb_lin, nb_lin+C) run hist2.
__global__ void __launch_bounds__(256, 1)
lin0_hist_kernel(const float* __restrict__ x, const float* __restrict__ w0,
                 const float* __restrict__ b0, const float* __restrict__ fcw,
                 const float* __restrict__ al, const float* __restrict__ ar,
                 float* __restrict__ h, f16* __restrict__ packed,
                 float* __restrict__ er, int n, int nb_lin,
                 const int* __restrict__ dst, int* __restrict__ M, int E, int C,
                 int np) {
    int t = threadIdx.x;
    if ((int)blockIdx.x >= nb_lin) {
        // ---- hist2 role ----
        __shared__ int hcnt[512];
        int c = blockIdx.x - nb_lin;
        for (int i = t; i < 512; i += 256) hcnt[i] = 0;
        __syncthreads();
        int i0 = c * PCHUNK;
        int i1 = min(i0 + PCHUNK, E);
        for (int i = i0 + t; i < i1; i += 256)
            atomicAdd(&hcnt[dst[i] >> PSHIFT], 1);
        __syncthreads();
        for (int b = t; b < np; b += 256)
            M[(size_t)b * C + c] = hcnt[b];
        return;
    }
    // ---- lin0tr role ----
    __shared__ float W0[HID * HID];
    __shared__ float W1[HID * HID];
    __shared__ float Bs[HID], ALs[HID], ARs[HID];
    for (int i = t; i < HID * HID; i += 256) { W0[i] = w0[i]; W1[i] = fcw[i]; }
    if (t < HID) { Bs[t] = b0[t]; ALs[t] = al[t]; ARs[t] = ar[t]; }
    __syncthreads();
    int node = blockIdx.x * 256 + t;
    if (node >= n) return;
    const float4* xp = (const float4*)(x + (size_t)node * HID);
    float h0[HID];
#pragma unroll
    for (int j = 0; j < HID; ++j) h0[j] = Bs[j];
#pragma unroll
    for (int kk = 0; kk < HID / 4; ++kk) {
        float4 xv = xp[kk];
        const float* w = &W0[(4 * kk) * HID];
#pragma unroll
        for (int j = 0; j < HID; ++j)
            h0[j] += xv.x * w[j] + xv.y * w[HID + j] + xv.z * w[2 * HID + j] + xv.w * w[3 * HID + j];
    }
    float* hp = h + (size_t)node * HID;
#pragma unroll
    for (int j = 0; j < HID; ++j) hp[j] = h0[j];
    float feat[HID];
#pragma unroll
    for (int j = 0; j < HID; ++j) feat[j] = 0.f;
#pragma unroll
    for (int k = 0; k < HID; ++k) {
        float hv = h0[k];
        const float* w = &W1[k * HID];
#pragma unroll
        for (int j = 0; j < HID; ++j) feat[j] += hv * w[j];
    }
    union { f16 hx[48]; uint4 q[6]; } u;
#pragma unroll
    for (int hh = 0; hh < NH; ++hh) {
        float sl = 0.f, sr = 0.f;
#pragma unroll
        for (int d = 0; d < HD; ++d) {
            sl += feat[hh * HD + d] * ALs[hh * HD + d];
            sr += feat[hh * HD + d] * ARs[hh * HD + d];
        }
#pragma unroll
        for (int d = 0; d < HD; ++d) u.hx[hh * 16 + d] = (f16)feat[hh * HD + d];
        u.hx[hh * 16 + 12] = (f16)sl;
        u.hx[hh * 16 + 13] = (f16)0.f;
        u.hx[hh * 16 + 14] = (f16)0.f;
        u.hx[hh * 16 + 15] = (f16)0.f;
        er[node * NH + hh] = sr;
    }
    uint4* prow = (uint4*)(packed + (size_t)node * PROW);
#pragma unroll
    for (int q = 0; q < 6; ++q) prow[q] = u.q[q];
}

// per-partition exclusive scan over C chunks (multi-round, 512 thr, carry)
__global__ void base_scan_kernel(const int* __restrict__ M, int* __restrict__ BaseT,
                                 int* __restrict__ T, int C, int np) {
    __shared__ int tmp[512];
    int b = blockIdx.x;
    int t = threadIdx.x;
    int carry = 0;
    for (int base = 0; base < C; base += 512) {
        int idx = base + t;
        int v = (idx < C) ? M[(size_t)b * C + idx] : 0;
        tmp[t] = v;
        __syncthreads();
        for (int ofs = 1; ofs < 512; ofs <<= 1) {
            int x = 0;
            if (t >= ofs) x = tmp[t - ofs];
            __syncthreads();
            tmp[t] += x;
            __syncthreads();
        }
        if (idx < C) BaseT[(size_t)idx * 512 + b] = carry + tmp[t] - v;
        carry += tmp[511];
        __syncthreads();
    }
    if (t == 0) T[b] = carry;
}

// scatter edges into partition windows via LDS reorder -> coalesced write.
// poff = excl-scan(T) recomputed in-block (scan_small stays deleted).
__global__ void part_scatter_kernel(const int* __restrict__ src, const int* __restrict__ dst,
                                    const int* __restrict__ BaseT, const int* __restrict__ T,
                                    int* __restrict__ part, int E, int np) {
    __shared__ int tsc[512];
    __shared__ int base[512];
    __shared__ int hexcl[512];
    __shared__ int hcur[512];
    __shared__ int smsrc[PCHUNK];
    __shared__ int smdst[PCHUNK];
    __shared__ int smsort[PCHUNK];
    __shared__ short smbin[PCHUNK];
    int t = threadIdx.x;
    int c = blockIdx.x;
    // poff scan of T + window bases
    int v = (t < np) ? T[t] : 0;
    tsc[t] = v;
    hcur[t] = 0;
    __syncthreads();
    for (int ofs = 1; ofs < 512; ofs <<= 1) {
        int x = 0;
        if (t >= ofs) x = tsc[t - ofs];
        __syncthreads();
        tsc[t] += x;
        __syncthreads();
    }
    if (t < np) base[t] = (tsc[t] - v) + BaseT[(size_t)c * 512 + t];
    __syncthreads();
    int i0 = c * PCHUNK;
    int cnum = min(i0 + PCHUNK, E) - i0;
    // load chunk + count bins
    for (int i = t; i < cnum; i += 512) {
        int s = src[i0 + i], d = dst[i0 + i];
        smsrc[i] = s;
        smdst[i] = d;
        atomicAdd(&hcur[d >> PSHIFT], 1);
    }
    __syncthreads();
    // exclusive scan of per-chunk bin counts
    int hv = hcur[t];
    tsc[t] = hv;
    __syncthreads();
    for (int ofs = 1; ofs < 512; ofs <<= 1) {
        int x = 0;
        if (t >= ofs) x = tsc[t - ofs];
        __syncthreads();
        tsc[t] += x;
        __syncthreads();
    }
    hexcl[t] = tsc[t] - hv;
    hcur[t] = tsc[t] - hv;   // cursors start at excl
    __syncthreads();
    // scatter within LDS (banked, cheap)
    for (int i = t; i < cnum; i += 512) {
        int d = smdst[i];
        int bin = d >> PSHIFT;
        int pos = atomicAdd(&hcur[bin], 1);
        smsort[pos] = (smsrc[i] << PSHIFT) | (d & ((1 << PSHIFT) - 1));
        smbin[pos] = (short)bin;
    }
    __syncthreads();
    // coalesced write: consecutive i share bin spans -> few lines per wave
    for (int i = t; i < cnum; i += 512) {
        int bin = smbin[i];
        part[base[bin] + (i - hexcl[bin])] = smsort[i];
    }
}

// one block per partition: LDS counting sort by (dst_local, src_bucket).
// Scatter lands in LDS smout; csr written with one coalesced sweep.
__global__ void bucket_csr_kernel(const int* __restrict__ part, const int* __restrict__ T,
                                  int* __restrict__ csr, int* __restrict__ off,
                                  int n, int E, int np) {
    __shared__ int cnt[256 * NBUCK];
    __shared__ int psum[512];
    __shared__ int smout[SPCAP];
    __shared__ int e0s;
    int p = blockIdx.x;
    int t = threadIdx.x;
    // in-block exclusive scan of T to get e0 = poff[p]
    int v = (t < np) ? T[t] : 0;
    psum[t] = v;
    __syncthreads();
    for (int ofs = 1; ofs < 512; ofs <<= 1) {
        int x = 0;
        if (t >= ofs) x = psum[t - ofs];
        __syncthreads();
        psum[t] += x;
        __syncthreads();
    }
    if (t == p) e0s = psum[t] - v;
    __syncthreads();
    int e0 = e0s;
    int dbase = p << PSHIFT;
    int nd = min(256, n - dbase);
    int nc = nd * NBUCK;
    for (int i = t; i < nc; i += blockDim.x) cnt[i] = 0;
    __syncthreads();
    int cnt_p = T[p];
    const int* pp = part + e0;
    bool fits = (cnt_p <= SPCAP);
    for (int i = t; i < cnt_p; i += blockDim.x) {
        int e = pp[i];
        atomicAdd(&cnt[(e & 255) * NBUCK + ((e >> PSHIFT) >> BSHIFT)], 1);
    }
    __syncthreads();
    int sum = 0;
    if (t < nd) {
        for (int k = 0; k < NBUCK; ++k) {
            int c = cnt[t * NBUCK + k];
            cnt[t * NBUCK + k] = sum;
            sum += c;
        }
    }
    psum[t] = (t < nd) ? sum : 0;
    __syncthreads();
    for (int ofs = 1; ofs < 512; ofs <<= 1) {
        int x = 0;
        if (t >= ofs) x = psum[t - ofs];
        __syncthreads();
        psum[t] += x;
        __syncthreads();
    }
    int dexcl = (t > 0) ? psum[t - 1] : 0;
    int start = e0 + dexcl;
    if (t < nd) {
        for (int k = 0; k < NBUCK; ++k) cnt[t * NBUCK + k] += start;
        off[dbase + t] = start;
    }
    __syncthreads();
    if (fits) {
        // scatter into LDS (pos-e0 in [0,cnt_p)), then coalesced csr write
        for (int i = t; i < cnt_p; i += blockDim.x) {
            int e = pp[i];
            int s = e >> PSHIFT;
            int idx = (e & 255) * NBUCK + (s >> BSHIFT);
            int pos = atomicAdd(&cnt[idx], 1);
            smout[pos - e0] = s << 6;   // s * PROW
        }
        __syncthreads();
        for (int i = t; i < cnt_p; i += blockDim.x)
            csr[e0 + i] = smout[i];
    } else {
        for (int i = t; i < cnt_p; i += blockDim.x) {
            int e = pp[i];
            int s = e >> PSHIFT;
            int idx = (e & 255) * NBUCK + (s >> BSHIFT);
            int pos = atomicAdd(&cnt[idx], 1);
            csr[pos] = s << 6;
        }
    }
    if (p == 0 && t == 0) off[n] = E;
}

// ---------------- fused node kernels (round-9/11 best agg config) ----------

__device__ __forceinline__ void edge_accum(uint4 qa, uint4 qb, float ern,
                                           float& denom, float* acc) {
    union { uint4 q[2]; f16 hx[16]; } v;
    v.q[0] = qa;
    v.q[1] = qb;
    float e = (float)v.hx[12] + ern;
    e = (e >= 0.f) ? e : 0.2f * e;
    float w = __expf(e);
    denom += w;
#pragma unroll
    for (int k = 0; k < HD; ++k) acc[k] += w * (float)v.hx[k];
}

// fraction-paced barrier-free sweep: NSTEP=8 supersteps (~1.6MB active set
// per XCD L2). Rows are one aligned 128B line.
template <bool FITS>
__device__ __forceinline__ void sweep_paced(const int* __restrict__ smbuf,
                                            const int* __restrict__ csre,
                                            int j0, int deg, const f16* __restrict__ pb,
                                            float ern, float& denom, float* acc) {
    int j = j0;
#pragma unroll 1
    for (int s2 = 1; s2 <= NSTEP; ++s2) {
        int jend = j0 + ((deg * s2) >> 3);   // NSTEP == 8
        int c = jend - j;
        for (; c >= 4; c -= 4, j += 4) {
            int o0 = FITS ? smbuf[j]     : csre[j];
            int o1 = FITS ? smbuf[j + 1] : csre[j + 1];
            int o2 = FITS ? smbuf[j + 2] : csre[j + 2];
            int o3 = FITS ? smbuf[j + 3] : csre[j + 3];
            const uint4* r0 = (const uint4*)(pb + o0);
            const uint4* r1 = (const uint4*)(pb + o1);
            const uint4* r2 = (const uint4*)(pb + o2);
            const uint4* r3 = (const uint4*)(pb + o3);
            uint4 a0 = r0[0], b0 = r0[1];
            uint4 a1 = r1[0], b1 = r1[1];
            uint4 a2 = r2[0], b2 = r2[1];
            uint4 a3 = r3[0], b3 = r3[1];
            edge_accum(a0, b0, ern, denom, acc);
            edge_accum(a1, b1, ern, denom, acc);
            edge_accum(a2, b2, ern, denom, acc);
            edge_accum(a3, b3, ern, denom, acc);
        }
        for (; c > 0; --c, ++j) {
            int o = FITS ? smbuf[j] : csre[j];
            const uint4* r = (const uint4*)(pb + o);
            edge_accum(r[0], r[1], ern, denom, acc);
        }
    }
}

// fused: paced barrier-free aggregate (csr staged in LDS, x4 unroll) ->
// hnext, then transform(l+1) via LDS exchange. 192 thr = 64 nodes x 3 heads.
__global__ void __launch_bounds__(192)
aggtr_kernel(const f16* __restrict__ packed_in, const float* __restrict__ er_in,
             const float* __restrict__ hcur,
             const int* __restrict__ off, const int* __restrict__ csr,
             const float* __restrict__ bias, const float* __restrict__ wnext,
             const float* __restrict__ aln, const float* __restrict__ arn,
             float* __restrict__ hnext, f16* __restrict__ packed_out,
             float* __restrict__ er_out, int n) {
    __shared__ float Wsh[HID * HID];
    __shared__ float ALs[HID], ARs[HID];
    __shared__ int smbuf[CSRCAP];  // csr span during sweep; hsh afterwards
    int t = threadIdx.x;
    for (int i = t; i < HID * HID; i += 192) Wsh[i] = wnext[i];
    if (t < HID) { ALs[t] = aln[t]; ARs[t] = arn[t]; }
    int ln = t / 3, hh = t - ln * 3;
    int nb0 = blockIdx.x * 64;
    int node = nb0 + ln;
    bool active = (node < n);

    int e0 = off[nb0];
    int e1 = off[min(nb0 + 64, n)];
    int span = e1 - e0;
    bool fits = (span <= CSRCAP);
    if (fits)
        for (int i = t; i < span; i += 192) smbuf[i] = csr[e0 + i];

    int j0 = 0, deg = 0;
    float ern = 0.f;
    if (active) {
        j0 = off[node] - e0;      // block-local csr index
        deg = off[node + 1] - e0 - j0;
        ern = er_in[node * NH + hh];
    }
    const f16* pb = packed_in + hh * 16;
    const int* csre = csr + e0;
    __syncthreads();

    float denom = 0.f;
    float acc[HD];
#pragma unroll
    for (int k = 0; k < HD; ++k) acc[k] = 0.f;

    if (fits) sweep_paced<true>(smbuf, csre, j0, deg, pb, ern, denom, acc);
    else      sweep_paced<false>(smbuf, csre, j0, deg, pb, ern, denom, acc);
    __syncthreads();  // all threads done reading smbuf before hsh reuse

    // epilogue: hnext = elu(acc/denom + hcur + bias); stage into hsh (=smbuf)
    float* hsh = (float*)smbuf;
    float v[HD];
#pragma unroll
    for (int k = 0; k < HD; ++k) v[k] = 0.f;
    if (active) {
        float inv = 1.f / fmaxf(denom, 1e-9f);
        int base = node * HID + hh * HD;
        const float4* hc = (const float4*)(hcur + base);
        float4 h0 = hc[0], h1 = hc[1], h2 = hc[2];
        float hres[HD] = {h0.x, h0.y, h0.z, h0.w, h1.x, h1.y, h1.z, h1.w, h2.x, h2.y, h2.z, h2.w};
#pragma unroll
        for (int k = 0; k < HD; ++k) {
            float x = acc[k] * inv + hres[k] + bias[hh * HD + k];
            v[k] = (x > 0.f) ? x : expm1f(x);
        }
        float4* hp = (float4*)(hnext + base);
        hp[0] = make_float4(v[0], v[1], v[2], v[3]);
        hp[1] = make_float4(v[4], v[5], v[6], v[7]);
        hp[2] = make_float4(v[8], v[9], v[10], v[11]);
    }
#pragma unroll
    for (int k = 0; k < HD; ++k) hsh[ln * 37 + hh * HD + k] = v[k];
    __syncthreads();

    // transform tail: feat12 = hsh[ln][:] @ Wsh[:, hh*12..], then el/er+pack
    float feat[HD];
#pragma unroll
    for (int d = 0; d < HD; ++d) feat[d] = 0.f;
    const float* hrow = &hsh[ln * 37];
#pragma unroll 4
    for (int k = 0; k < HID; ++k) {
        float hv = hrow[k];
        const float* w = &Wsh[k * HID + hh * HD];
#pragma unroll
        for (int d = 0; d < HD; ++d) feat[d] += hv * w[d];
    }
    if (!active) return;
    float sl = 0.f, sr = 0.f;
#pragma unroll
    for (int d = 0; d < HD; ++d) {
        sl += feat[d] * ALs[hh * HD + d];
        sr += feat[d] * ARs[hh * HD + d];
    }
    union { f16 hx[16]; uint4 q[2]; } o;
#pragma unroll
    for (int d = 0; d < HD; ++d) o.hx[d] = (f16)feat[d];
    o.hx[12] = (f16)sl;
    o.hx[13] = (f16)0.f; o.hx[14] = (f16)0.f; o.hx[15] = (f16)0.f;
    uint4* prow = (uint4*)(packed_out + (size_t)node * PROW + hh * 16);
    prow[0] = o.q[0];
    prow[1] = o.q[1];
    er_out[node * NH + hh] = sr;
}

// fused: aggregate(last layer) -> h3 (in-reg) -> out = h3@OW + ob
__global__ void __launch_bounds__(192)
aggout_kernel(const f16* __restrict__ packed_in, const float* __restrict__ er_in,
              const float* __restrict__ hcur,
              const int* __restrict__ off, const int* __restrict__ csr,
              const float* __restrict__ bias, const float* __restrict__ ow,
              const float* __restrict__ ob, float* __restrict__ out, int n) {
    __shared__ float Wsh[HID * HID];
    __shared__ float OBs[HID];
    __shared__ int smbuf[CSRCAP];
    int t = threadIdx.x;
    for (int i = t; i < HID * HID; i += 192) Wsh[i] = ow[i];
    if (t < HID) OBs[t] = ob[t];
    int ln = t / 3, hh = t - ln * 3;
    int nb0 = blockIdx.x * 64;
    int node = nb0 + ln;
    bool active = (node < n);

    int e0 = off[nb0];
    int e1 = off[min(nb0 + 64, n)];
    int span = e1 - e0;
    bool fits = (span <= CSRCAP);
    if (fits)
        for (int i = t; i < span; i += 192) smbuf[i] = csr[e0 + i];

    int j0 = 0, deg = 0;
    float ern = 0.f;
    if (active) {
        j0 = off[node] - e0;
        deg = off[node + 1] - e0 - j0;
        ern = er_in[node * NH + hh];
    }
    const f16* pb = packed_in + hh * 16;
    const int* csre = csr + e0;
    __syncthreads();

    float denom = 0.f;
    float acc[HD];
#pragma unroll
    for (int k = 0; k < HD; ++k) acc[k] = 0.f;

    if (fits) sweep_paced<true>(smbuf, csre, j0, deg, pb, ern, denom, acc);
    else      sweep_paced<false>(smbuf, csre, j0, deg, pb, ern, denom, acc);
    __syncthreads();

    float* hsh = (float*)smbuf;
    float v[HD];
#pragma unroll
    for (int k = 0; k < HD; ++k) v[k] = 0.f;
    if (active) {
        float inv = 1.f / fmaxf(denom, 1e-9f);
        int base = node * HID + hh * HD;
        const float4* hc = (const float4*)(hcur + base);
        float4 h0 = hc[0], h1 = hc[1], h2 = hc[2];
        float hres[HD] = {h0.x, h0.y, h0.z, h0.w, h1.x, h1.y, h1.z, h1.w, h2.x, h2.y, h2.z, h2.w};
#pragma unroll
        for (int k = 0; k < HD; ++k) {
            float x = acc[k] * inv + hres[k] + bias[hh * HD + k];
            v[k] = (x > 0.f) ? x : expm1f(x);
        }
    }
#pragma unroll
    for (int k = 0; k < HD; ++k) hsh[ln * 37 + hh * HD + k] = v[k];
    __syncthreads();

    float feat[HD];
#pragma unroll
    for (int d = 0; d < HD; ++d) feat[d] = OBs[hh * HD + d];
    const float* hrow = &hsh[ln * 37];
#pragma unroll 4
    for (int k = 0; k < HID; ++k) {
        float hv = hrow[k];
        const float* w = &Wsh[k * HID + hh * HD];
#pragma unroll
        for (int d = 0; d < HD; ++d) feat[d] += hv * w[d];
    }
    if (!active) return;
    float4* op = (float4*)(out + (size_t)node * HID + hh * HD);
    op[0] = make_float4(feat[0], feat[1], feat[2], feat[3]);
    op[1] = make_float4(feat[4], feat[5], feat[6], feat[7]);
    op[2] = make_float4(feat[8], feat[9], feat[10], feat[11]);
}

// ---------------- launch ----------------

extern "C" void kernel_launch(void* const* d_in, const int* in_sizes, int n_in,
                              void* d_out, int out_size, void* d_ws, size_t ws_size,
                              hipStream_t stream) {
    const float* xnf = (const float*)d_in[0];
    const int* src = (const int*)d_in[1];
    const int* dst = (const int*)d_in[2];
    const float* l0w = (const float*)d_in[3];
    const float* l0b = (const float*)d_in[4];
    const float* fcw = (const float*)d_in[5];
    const float* al  = (const float*)d_in[6];
    const float* ar  = (const float*)d_in[7];
    const float* gb  = (const float*)d_in[8];
    const float* ow  = (const float*)d_in[9];
    const float* ob  = (const float*)d_in[10];
    float* out = (float*)d_out;
    const int N = in_sizes[0] / HID;
    const int E = in_sizes[1];
    const int NP = (N + (1 << PSHIFT) - 1) >> PSHIFT;  // 391 dst partitions
    const int C = (E + PCHUNK - 1) / PCHUNK;           // 1563 chunks

    char* p = (char*)d_ws;
    auto alloc = [&](size_t bytes) {
        char* r = p;
        p += (bytes + 255) & ~(size_t)255;
        return r;
    };
    int* part    = (int*)alloc((size_t)E * 4);
    int* M       = (int*)alloc((size_t)NP * C * 4);
    int* BaseT   = (int*)alloc((size_t)C * 512 * 4);
    int* T       = (int*)alloc((size_t)NP * 4);
    int* off     = (int*)alloc((size_t)(N + 1) * 4);
    int* csr     = (int*)alloc((size_t)E * 4);
    float* ha    = (float*)alloc((size_t)N * HID * 4);
    float* hb    = (float*)alloc((size_t)N * HID * 4);
    f16* pkA     = (f16*)alloc((size_t)N * PROW * 2);
    f16* pkB     = (f16*)alloc((size_t)N * PROW * 2);
    float* erA   = (float*)alloc((size_t)N * NH * 4);
    float* erB   = (float*)alloc((size_t)N * NH * 4);

    int nblk = (N + 255) / 256;
    int fblk = (N + 63) / 64;

    // fused lin0tr + hist2 (independent workloads, one launch)
    lin0_hist_kernel<<<nblk + C, 256, 0, stream>>>(xnf, l0w, l0b, fcw, al, ar,
                                                   ha, pkA, erA, N, nblk,
                                                   dst, M, E, C, NP);
    base_scan_kernel<<<NP, 512, 0, stream>>>(M, BaseT, T, C, NP);
    part_scatter_kernel<<<C, 512, 0, stream>>>(src, dst, BaseT, T, part, E, NP);
    bucket_csr_kernel<<<NP, 512, 0, stream>>>(part, T, csr, off, N, E, NP);

    // layer0 aggregate + transform(layer1)
    aggtr_kernel<<<fblk, 192, 0, stream>>>(pkA, erA, ha, off, csr, gb,
                                           fcw + (size_t)1 * HID * HID, al + HID, ar + HID,
                                           hb, pkB, erB, N);
    // layer1 aggregate + transform(layer2)
    aggtr_kernel<<<fblk, 192, 0, stream>>>(pkB, erB, hb, off, csr, gb + HID,
                                           fcw + (size_t)2 * HID * HID, al + 2 * HID, ar + 2 * HID,
                                           ha, pkA, erA, N);
    // layer2 aggregate + out GEMM (h3 never materialized)
    aggout_kernel<<<fblk, 192, 0, stream>>>(pkA, erA, ha, off, csr, gb + 2 * HID,
                                            ow, ob, out, N);
}

// Round 13
// 336.597 us; speedup vs baseline: 1.1568x; 1.0023x over previous
//
#include <hip/hip_runtime.h>
#include <math.h>

#define HID 36
#define NH 3
#define HD 12
#define PROW 64     // f16 units per packed row: 128B, one aligned L2 line
#define BSHIFT 13   // src-bucket = src >> 13 (13 buckets; sort kept for locality)
#define NBUCK 13
#define PSHIFT 8    // dst partition = dst >> 8 (256 dsts per partition)
#define PCHUNK 2048 // edges per chunk in partition pass
#define SPCAP 9216  // LDS reorder buffer per partition (mean 8192, sigma ~90)
#define CSRCAP 4096 // LDS-staged csr entries per agg block (mean 2048, sigma 45)
#define NSTEP 8     // fraction-paced supersteps (r10: NSTEP=4/x8 regressed — L2 overflow)

typedef _Float16 f16;

// ---------------- CSR build: atomic-free two-level partition sort ----------
// r12: both scatter passes reorder in LDS first, then write global COALESCED.
// r13: lin0 role restructured 3-threads-per-node (live set ~40 VGPR) — the
// monolithic per-thread GEMM pair spilled at VGPR=116 (r8/r12 signature:
// 67us at 8% VALU, 19% occ; floor is ~15us).

// fused: blocks [0,nb_lin) run lin0tr (64 nodes x 3 heads per block);
// blocks [nb_lin, nb_lin+C) run hist2.
__global__ void __launch_bounds__(192)
lin0_hist_kernel(const float* __restrict__ x, const float* __restrict__ w0,
                 const float* __restrict__ b0, const float* __restrict__ fcw,
                 const float* __restrict__ al, const float* __restrict__ ar,
                 float* __restrict__ h, f16* __restrict__ packed,
                 float* __restrict__ er, int n, int nb_lin,
                 const int* __restrict__ dst, int* __restrict__ M, int E, int C,
                 int np) {
    int t = threadIdx.x;
    if ((int)blockIdx.x >= nb_lin) {
        // ---- hist2 role ----
        __shared__ int hcnt[512];
        int c = blockIdx.x - nb_lin;
        for (int i = t; i < 512; i += 192) hcnt[i] = 0;
        __syncthreads();
        int i0 = c * PCHUNK;
        int i1 = min(i0 + PCHUNK, E);
        for (int i = i0 + t; i < i1; i += 192)
            atomicAdd(&hcnt[dst[i] >> PSHIFT], 1);
        __syncthreads();
        for (int b = t; b < np; b += 192)
            M[(size_t)b * C + c] = hcnt[b];
        return;
    }
    // ---- lin0tr role: 192 thr = 64 nodes x 3 heads ----
    __shared__ float W0[HID * HID];
    __shared__ float W1[HID * HID];
    __shared__ float Bs[HID], ALs[HID], ARs[HID];
    __shared__ float xsh[64 * 37];
    __shared__ float hsh[64 * 37];
    for (int i = t; i < HID * HID; i += 192) { W0[i] = w0[i]; W1[i] = fcw[i]; }
    if (t < HID) { Bs[t] = b0[t]; ALs[t] = al[t]; ARs[t] = ar[t]; }
    int nb0 = blockIdx.x * 64;
    int nrow = min(64, n - nb0);
    for (int i = t; i < nrow * HID; i += 192) {
        int r = i / HID, cc = i - r * HID;
        xsh[r * 37 + cc] = x[(size_t)nb0 * HID + i];
        (void)cc;
    }
    __syncthreads();
    int ln = t / 3, hh = t - ln * 3;
    int node = nb0 + ln;
    bool active = (node < n);

    // h0 slice: h0s[d] = b0[hh*12+d] + sum_k x[k] * W0[k][hh*12+d]
    float h0s[HD];
#pragma unroll
    for (int d = 0; d < HD; ++d) h0s[d] = Bs[hh * HD + d];
    const float* xrow = &xsh[ln * 37];
#pragma unroll 4
    for (int k = 0; k < HID; ++k) {
        float xv = xrow[k];
        const float* w = &W0[k * HID + hh * HD];
#pragma unroll
        for (int d = 0; d < HD; ++d) h0s[d] += xv * w[d];
    }
    if (active) {
        float4* hp = (float4*)(h + (size_t)node * HID + hh * HD);
        hp[0] = make_float4(h0s[0], h0s[1], h0s[2], h0s[3]);
        hp[1] = make_float4(h0s[4], h0s[5], h0s[6], h0s[7]);
        hp[2] = make_float4(h0s[8], h0s[9], h0s[10], h0s[11]);
    }
#pragma unroll
    for (int d = 0; d < HD; ++d) hsh[ln * 37 + hh * HD + d] = h0s[d];
    __syncthreads();

    // feat slice: feat[d] = sum_k h0[k] * W1[k][hh*12+d]
    float feat[HD];
#pragma unroll
    for (int d = 0; d < HD; ++d) feat[d] = 0.f;
    const float* hrow = &hsh[ln * 37];
#pragma unroll 4
    for (int k = 0; k < HID; ++k) {
        float hv = hrow[k];
        const float* w = &W1[k * HID + hh * HD];
#pragma unroll
        for (int d = 0; d < HD; ++d) feat[d] += hv * w[d];
    }
    if (!active) return;
    float sl = 0.f, sr = 0.f;
#pragma unroll
    for (int d = 0; d < HD; ++d) {
        sl += feat[d] * ALs[hh * HD + d];
        sr += feat[d] * ARs[hh * HD + d];
    }
    union { f16 hx[16]; uint4 q[2]; } o;
#pragma unroll
    for (int d = 0; d < HD; ++d) o.hx[d] = (f16)feat[d];
    o.hx[12] = (f16)sl;
    o.hx[13] = (f16)0.f; o.hx[14] = (f16)0.f; o.hx[15] = (f16)0.f;
    uint4* prow = (uint4*)(packed + (size_t)node * PROW + hh * 16);
    prow[0] = o.q[0];
    prow[1] = o.q[1];
    er[node * NH + hh] = sr;
}

// per-partition exclusive scan over C chunks (multi-round, 512 thr, carry)
__global__ void base_scan_kernel(const int* __restrict__ M, int* __restrict__ BaseT,
                                 int* __restrict__ T, int C, int np) {
    __shared__ int tmp[512];
    int b = blockIdx.x;
    int t = threadIdx.x;
    int carry = 0;
    for (int base = 0; base < C; base += 512) {
        int idx = base + t;
        int v = (idx < C) ? M[(size_t)b * C + idx] : 0;
        tmp[t] = v;
        __syncthreads();
        for (int ofs = 1; ofs < 512; ofs <<= 1) {
            int x = 0;
            if (t >= ofs) x = tmp[t - ofs];
            __syncthreads();
            tmp[t] += x;
            __syncthreads();
        }
        if (idx < C) BaseT[(size_t)idx * 512 + b] = carry + tmp[t] - v;
        carry += tmp[511];
        __syncthreads();
    }
    if (t == 0) T[b] = carry;
}

// scatter edges into partition windows via LDS reorder -> coalesced write.
__global__ void part_scatter_kernel(const int* __restrict__ src, const int* __restrict__ dst,
                                    const int* __restrict__ BaseT, const int* __restrict__ T,
                                    int* __restrict__ part, int E, int np) {
    __shared__ int tsc[512];
    __shared__ int base[512];
    __shared__ int hexcl[512];
    __shared__ int hcur[512];
    __shared__ int smsrc[PCHUNK];
    __shared__ int smdst[PCHUNK];
    __shared__ int smsort[PCHUNK];
    __shared__ short smbin[PCHUNK];
    int t = threadIdx.x;
    int c = blockIdx.x;
    int v = (t < np) ? T[t] : 0;
    tsc[t] = v;
    hcur[t] = 0;
    __syncthreads();
    for (int ofs = 1; ofs < 512; ofs <<= 1) {
        int x = 0;
        if (t >= ofs) x = tsc[t - ofs];
        __syncthreads();
        tsc[t] += x;
        __syncthreads();
    }
    if (t < np) base[t] = (tsc[t] - v) + BaseT[(size_t)c * 512 + t];
    __syncthreads();
    int i0 = c * PCHUNK;
    int cnum = min(i0 + PCHUNK, E) - i0;
    for (int i = t; i < cnum; i += 512) {
        int s = src[i0 + i], d = dst[i0 + i];
        smsrc[i] = s;
        smdst[i] = d;
        atomicAdd(&hcur[d >> PSHIFT], 1);
    }
    __syncthreads();
    int hv = hcur[t];
    tsc[t] = hv;
    __syncthreads();
    for (int ofs = 1; ofs < 512; ofs <<= 1) {
        int x = 0;
        if (t >= ofs) x = tsc[t - ofs];
        __syncthreads();
        tsc[t] += x;
        __syncthreads();
    }
    hexcl[t] = tsc[t] - hv;
    hcur[t] = tsc[t] - hv;
    __syncthreads();
    for (int i = t; i < cnum; i += 512) {
        int d = smdst[i];
        int bin = d >> PSHIFT;
        int pos = atomicAdd(&hcur[bin], 1);
        smsort[pos] = (smsrc[i] << PSHIFT) | (d & ((1 << PSHIFT) - 1));
        smbin[pos] = (short)bin;
    }
    __syncthreads();
    for (int i = t; i < cnum; i += 512) {
        int bin = smbin[i];
        part[base[bin] + (i - hexcl[bin])] = smsort[i];
    }
}

// one block per partition: LDS counting sort by (dst_local, src_bucket).
// Scatter lands in LDS smout; csr written with one coalesced sweep.
__global__ void bucket_csr_kernel(const int* __restrict__ part, const int* __restrict__ T,
                                  int* __restrict__ csr, int* __restrict__ off,
                                  int n, int E, int np) {
    __shared__ int cnt[256 * NBUCK];
    __shared__ int psum[512];
    __shared__ int smout[SPCAP];
    __shared__ int e0s;
    int p = blockIdx.x;
    int t = threadIdx.x;
    int v = (t < np) ? T[t] : 0;
    psum[t] = v;
    __syncthreads();
    for (int ofs = 1; ofs < 512; ofs <<= 1) {
        int x = 0;
        if (t >= ofs) x = psum[t - ofs];
        __syncthreads();
        psum[t] += x;
        __syncthreads();
    }
    if (t == p) e0s = psum[t] - v;
    __syncthreads();
    int e0 = e0s;
    int dbase = p << PSHIFT;
    int nd = min(256, n - dbase);
    int nc = nd * NBUCK;
    for (int i = t; i < nc; i += blockDim.x) cnt[i] = 0;
    __syncthreads();
    int cnt_p = T[p];
    const int* pp = part + e0;
    bool fits = (cnt_p <= SPCAP);
    for (int i = t; i < cnt_p; i += blockDim.x) {
        int e = pp[i];
        atomicAdd(&cnt[(e & 255) * NBUCK + ((e >> PSHIFT) >> BSHIFT)], 1);
    }
    __syncthreads();
    int sum = 0;
    if (t < nd) {
        for (int k = 0; k < NBUCK; ++k) {
            int c = cnt[t * NBUCK + k];
            cnt[t * NBUCK + k] = sum;
            sum += c;
        }
    }
    psum[t] = (t < nd) ? sum : 0;
    __syncthreads();
    for (int ofs = 1; ofs < 512; ofs <<= 1) {
        int x = 0;
        if (t >= ofs) x = psum[t - ofs];
        __syncthreads();
        psum[t] += x;
        __syncthreads();
    }
    int dexcl = (t > 0) ? psum[t - 1] : 0;
    int start = e0 + dexcl;
    if (t < nd) {
        for (int k = 0; k < NBUCK; ++k) cnt[t * NBUCK + k] += start;
        off[dbase + t] = start;
    }
    __syncthreads();
    if (fits) {
        for (int i = t; i < cnt_p; i += blockDim.x) {
            int e = pp[i];
            int s = e >> PSHIFT;
            int idx = (e & 255) * NBUCK + (s >> BSHIFT);
            int pos = atomicAdd(&cnt[idx], 1);
            smout[pos - e0] = s << 6;   // s * PROW
        }
        __syncthreads();
        for (int i = t; i < cnt_p; i += blockDim.x)
            csr[e0 + i] = smout[i];
    } else {
        for (int i = t; i < cnt_p; i += blockDim.x) {
            int e = pp[i];
            int s = e >> PSHIFT;
            int idx = (e & 255) * NBUCK + (s >> BSHIFT);
            int pos = atomicAdd(&cnt[idx], 1);
            csr[pos] = s << 6;
        }
    }
    if (p == 0 && t == 0) off[n] = E;
}

// ---------------- fused node kernels (round-9/11 best agg config) ----------

__device__ __forceinline__ void edge_accum(uint4 qa, uint4 qb, float ern,
                                           float& denom, float* acc) {
    union { uint4 q[2]; f16 hx[16]; } v;
    v.q[0] = qa;
    v.q[1] = qb;
    float e = (float)v.hx[12] + ern;
    e = (e >= 0.f) ? e : 0.2f * e;
    float w = __expf(e);
    denom += w;
#pragma unroll
    for (int k = 0; k < HD; ++k) acc[k] += w * (float)v.hx[k];
}

// fraction-paced barrier-free sweep: NSTEP=8 supersteps (~1.6MB active set
// per XCD L2). Rows are one aligned 128B line.
template <bool FITS>
__device__ __forceinline__ void sweep_paced(const int* __restrict__ smbuf,
                                            const int* __restrict__ csre,
                                            int j0, int deg, const f16* __restrict__ pb,
                                            float ern, float& denom, float* acc) {
    int j = j0;
#pragma unroll 1
    for (int s2 = 1; s2 <= NSTEP; ++s2) {
        int jend = j0 + ((deg * s2) >> 3);   // NSTEP == 8
        int c = jend - j;
        for (; c >= 4; c -= 4, j += 4) {
            int o0 = FITS ? smbuf[j]     : csre[j];
            int o1 = FITS ? smbuf[j + 1] : csre[j + 1];
            int o2 = FITS ? smbuf[j + 2] : csre[j + 2];
            int o3 = FITS ? smbuf[j + 3] : csre[j + 3];
            const uint4* r0 = (const uint4*)(pb + o0);
            const uint4* r1 = (const uint4*)(pb + o1);
            const uint4* r2 = (const uint4*)(pb + o2);
            const uint4* r3 = (const uint4*)(pb + o3);
            uint4 a0 = r0[0], b0 = r0[1];
            uint4 a1 = r1[0], b1 = r1[1];
            uint4 a2 = r2[0], b2 = r2[1];
            uint4 a3 = r3[0], b3 = r3[1];
            edge_accum(a0, b0, ern, denom, acc);
            edge_accum(a1, b1, ern, denom, acc);
            edge_accum(a2, b2, ern, denom, acc);
            edge_accum(a3, b3, ern, denom, acc);
        }
        for (; c > 0; --c, ++j) {
            int o = FITS ? smbuf[j] : csre[j];
            const uint4* r = (const uint4*)(pb + o);
            edge_accum(r[0], r[1], ern, denom, acc);
        }
    }
}

// fused: paced barrier-free aggregate (csr staged in LDS, x4 unroll) ->
// hnext, then transform(l+1) via LDS exchange. 192 thr = 64 nodes x 3 heads.
__global__ void __launch_bounds__(192)
aggtr_kernel(const f16* __restrict__ packed_in, const float* __restrict__ er_in,
             const float* __restrict__ hcur,
             const int* __restrict__ off, const int* __restrict__ csr,
             const float* __restrict__ bias, const float* __restrict__ wnext,
             const float* __restrict__ aln, const float* __restrict__ arn,
             float* __restrict__ hnext, f16* __restrict__ packed_out,
             float* __restrict__ er_out, int n) {
    __shared__ float Wsh[HID * HID];
    __shared__ float ALs[HID], ARs[HID];
    __shared__ int smbuf[CSRCAP];  // csr span during sweep; hsh afterwards
    int t = threadIdx.x;
    for (int i = t; i < HID * HID; i += 192) Wsh[i] = wnext[i];
    if (t < HID) { ALs[t] = aln[t]; ARs[t] = arn[t]; }
    int ln = t / 3, hh = t - ln * 3;
    int nb0 = blockIdx.x * 64;
    int node = nb0 + ln;
    bool active = (node < n);

    int e0 = off[nb0];
    int e1 = off[min(nb0 + 64, n)];
    int span = e1 - e0;
    bool fits = (span <= CSRCAP);
    if (fits)
        for (int i = t; i < span; i += 192) smbuf[i] = csr[e0 + i];

    int j0 = 0, deg = 0;
    float ern = 0.f;
    if (active) {
        j0 = off[node] - e0;      // block-local csr index
        deg = off[node + 1] - e0 - j0;
        ern = er_in[node * NH + hh];
    }
    const f16* pb = packed_in + hh * 16;
    const int* csre = csr + e0;
    __syncthreads();

    float denom = 0.f;
    float acc[HD];
#pragma unroll
    for (int k = 0; k < HD; ++k) acc[k] = 0.f;

    if (fits) sweep_paced<true>(smbuf, csre, j0, deg, pb, ern, denom, acc);
    else      sweep_paced<false>(smbuf, csre, j0, deg, pb, ern, denom, acc);
    __syncthreads();  // all threads done reading smbuf before hsh reuse

    // epilogue: hnext = elu(acc/denom + hcur + bias); stage into hsh (=smbuf)
    float* hsh = (float*)smbuf;
    float v[HD];
#pragma unroll
    for (int k = 0; k < HD; ++k) v[k] = 0.f;
    if (active) {
        float inv = 1.f / fmaxf(denom, 1e-9f);
        int base = node * HID + hh * HD;
        const float4* hc = (const float4*)(hcur + base);
        float4 h0 = hc[0], h1 = hc[1], h2 = hc[2];
        float hres[HD] = {h0.x, h0.y, h0.z, h0.w, h1.x, h1.y, h1.z, h1.w, h2.x, h2.y, h2.z, h2.w};
#pragma unroll
        for (int k = 0; k < HD; ++k) {
            float x = acc[k] * inv + hres[k] + bias[hh * HD + k];
            v[k] = (x > 0.f) ? x : expm1f(x);
        }
        float4* hp = (float4*)(hnext + base);
        hp[0] = make_float4(v[0], v[1], v[2], v[3]);
        hp[1] = make_float4(v[4], v[5], v[6], v[7]);
        hp[2] = make_float4(v[8], v[9], v[10], v[11]);
    }
#pragma unroll
    for (int k = 0; k < HD; ++k) hsh[ln * 37 + hh * HD + k] = v[k];
    __syncthreads();

    // transform tail: feat12 = hsh[ln][:] @ Wsh[:, hh*12..], then el/er+pack
    float feat[HD];
#pragma unroll
    for (int d = 0; d < HD; ++d) feat[d] = 0.f;
    const float* hrow = &hsh[ln * 37];
#pragma unroll 4
    for (int k = 0; k < HID; ++k) {
        float hv = hrow[k];
        const float* w = &Wsh[k * HID + hh * HD];
#pragma unroll
        for (int d = 0; d < HD; ++d) feat[d] += hv * w[d];
    }
    if (!active) return;
    float sl = 0.f, sr = 0.f;
#pragma unroll
    for (int d = 0; d < HD; ++d) {
        sl += feat[d] * ALs[hh * HD + d];
        sr += feat[d] * ARs[hh * HD + d];
    }
    union { f16 hx[16]; uint4 q[2]; } o;
#pragma unroll
    for (int d = 0; d < HD; ++d) o.hx[d] = (f16)feat[d];
    o.hx[12] = (f16)sl;
    o.hx[13] = (f16)0.f; o.hx[14] = (f16)0.f; o.hx[15] = (f16)0.f;
    uint4* prow = (uint4*)(packed_out + (size_t)node * PROW + hh * 16);
    prow[0] = o.q[0];
    prow[1] = o.q[1];
    er_out[node * NH + hh] = sr;
}

// fused: aggregate(last layer) -> h3 (in-reg) -> out = h3@OW + ob
__global__ void __launch_bounds__(192)
aggout_kernel(const f16* __restrict__ packed_in, const float* __restrict__ er_in,
              const float* __restrict__ hcur,
              const int* __restrict__ off, const int* __restrict__ csr,
              const float* __restrict__ bias, const float* __restrict__ ow,
              const float* __restrict__ ob, float* __restrict__ out, int n) {
    __shared__ float Wsh[HID * HID];
    __shared__ float OBs[HID];
    __shared__ int smbuf[CSRCAP];
    int t = threadIdx.x;
    for (int i = t; i < HID * HID; i += 192) Wsh[i] = ow[i];
    if (t < HID) OBs[t] = ob[t];
    int ln = t / 3, hh = t - ln * 3;
    int nb0 = blockIdx.x * 64;
    int node = nb0 + ln;
    bool active = (node < n);

    int e0 = off[nb0];
    int e1 = off[min(nb0 + 64, n)];
    int span = e1 - e0;
    bool fits = (span <= CSRCAP);
    if (fits)
        for (int i = t; i < span; i += 192) smbuf[i] = csr[e0 + i];

    int j0 = 0, deg = 0;
    float ern = 0.f;
    if (active) {
        j0 = off[node] - e0;
        deg = off[node + 1] - e0 - j0;
        ern = er_in[node * NH + hh];
    }
    const f16* pb = packed_in + hh * 16;
    const int* csre = csr + e0;
    __syncthreads();

    float denom = 0.f;
    float acc[HD];
#pragma unroll
    for (int k = 0; k < HD; ++k) acc[k] = 0.f;

    if (fits) sweep_paced<true>(smbuf, csre, j0, deg, pb, ern, denom, acc);
    else      sweep_paced<false>(smbuf, csre, j0, deg, pb, ern, denom, acc);
    __syncthreads();

    float* hsh = (float*)smbuf;
    float v[HD];
#pragma unroll
    for (int k = 0; k < HD; ++k) v[k] = 0.f;
    if (active) {
        float inv = 1.f / fmaxf(denom, 1e-9f);
        int base = node * HID + hh * HD;
        const float4* hc = (const float4*)(hcur + base);
        float4 h0 = hc[0], h1 = hc[1], h2 = hc[2];
        float hres[HD] = {h0.x, h0.y, h0.z, h0.w, h1.x, h1.y, h1.z, h1.w, h2.x, h2.y, h2.z, h2.w};
#pragma unroll
        for (int k = 0; k < HD; ++k) {
            float x = acc[k] * inv + hres[k] + bias[hh * HD + k];
            v[k] = (x > 0.f) ? x : expm1f(x);
        }
    }
#pragma unroll
    for (int k = 0; k < HD; ++k) hsh[ln * 37 + hh * HD + k] = v[k];
    __syncthreads();

    float feat[HD];
#pragma unroll
    for (int d = 0; d < HD; ++d) feat[d] = OBs[hh * HD + d];
    const float* hrow = &hsh[ln * 37];
#pragma unroll 4
    for (int k = 0; k < HID; ++k) {
        float hv = hrow[k];
        const float* w = &Wsh[k * HID + hh * HD];
#pragma unroll
        for (int d = 0; d < HD; ++d) feat[d] += hv * w[d];
    }
    if (!active) return;
    float4* op = (float4*)(out + (size_t)node * HID + hh * HD);
    op[0] = make_float4(feat[0], feat[1], feat[2], feat[3]);
    op[1] = make_float4(feat[4], feat[5], feat[6], feat[7]);
    op[2] = make_float4(feat[8], feat[9], feat[10], feat[11]);
}

// ---------------- launch ----------------

extern "C" void kernel_launch(void* const* d_in, const int* in_sizes, int n_in,
                              void* d_out, int out_size, void* d_ws, size_t ws_size,
                              hipStream_t stream) {
    const float* xnf = (const float*)d_in[0];
    const int* src = (const int*)d_in[1];
    const int* dst = (const int*)d_in[2];
    const float* l0w = (const float*)d_in[3];
    const float* l0b = (const float*)d_in[4];
    const float* fcw = (const float*)d_in[5];
    const float* al  = (const float*)d_in[6];
    const float* ar  = (const float*)d_in[7];
    const float* gb  = (const float*)d_in[8];
    const float* ow  = (const float*)d_in[9];
    const float* ob  = (const float*)d_in[10];
    float* out = (float*)d_out;
    const int N = in_sizes[0] / HID;
    const int E = in_sizes[1];
    const int NP = (N + (1 << PSHIFT) - 1) >> PSHIFT;  // 391 dst partitions
    const int C = (E + PCHUNK - 1) / PCHUNK;           // 1563 chunks

    char* p = (char*)d_ws;
    auto alloc = [&](size_t bytes) {
        char* r = p;
        p += (bytes + 255) & ~(size_t)255;
        return r;
    };
    int* part    = (int*)alloc((size_t)E * 4);
    int* M       = (int*)alloc((size_t)NP * C * 4);
    int* BaseT   = (int*)alloc((size_t)C * 512 * 4);
    int* T       = (int*)alloc((size_t)NP * 4);
    int* off     = (int*)alloc((size_t)(N + 1) * 4);
    int* csr     = (int*)alloc((size_t)E * 4);
    float* ha    = (float*)alloc((size_t)N * HID * 4);
    float* hb    = (float*)alloc((size_t)N * HID * 4);
    f16* pkA     = (f16*)alloc((size_t)N * PROW * 2);
    f16* pkB     = (f16*)alloc((size_t)N * PROW * 2);
    float* erA   = (float*)alloc((size_t)N * NH * 4);
    float* erB   = (float*)alloc((size_t)N * NH * 4);

    int nblk_lin = (N + 63) / 64;   // 1563 lin0 blocks (64 nodes x 3 heads)
    int fblk = (N + 63) / 64;

    // fused lin0tr + hist2 (independent workloads, one launch)
    lin0_hist_kernel<<<nblk_lin + C, 192, 0, stream>>>(xnf, l0w, l0b, fcw, al, ar,
                                                       ha, pkA, erA, N, nblk_lin,
                                                       dst, M, E, C, NP);
    base_scan_kernel<<<NP, 512, 0, stream>>>(M, BaseT, T, C, NP);
    part_scatter_kernel<<<C, 512, 0, stream>>>(src, dst, BaseT, T, part, E, NP);
    bucket_csr_kernel<<<NP, 512, 0, stream>>>(part, T, csr, off, N, E, NP);

    // layer0 aggregate + transform(layer1)
    aggtr_kernel<<<fblk, 192, 0, stream>>>(pkA, erA, ha, off, csr, gb,
                                           fcw + (size_t)1 * HID * HID, al + HID, ar + HID,
                                           hb, pkB, erB, N);
    // layer1 aggregate + transform(layer2)
    aggtr_kernel<<<fblk, 192, 0, stream>>>(pkB, erB, hb, off, csr, gb + HID,
                                           fcw + (size_t)2 * HID * HID, al + 2 * HID, ar + 2 * HID,
                                           ha, pkA, erA, N);
    // layer2 aggregate + out GEMM (h3 never materialized)
    aggout_kernel<<<fblk, 192, 0, stream>>>(pkA, erA, ha, off, csr, gb + 2 * HID,
                                            ow, ob, out, N);
}